// Round 7
// baseline (409.359 us; speedup 1.0000x reference)
//
#include <hip/hip_runtime.h>
#include <math.h>

#define N_NODES 100000
#define N_EDGES 1600000
#define F_INDIM 256
#define HID 64
#define NCLS 40
#define NB_SCAN 391      // ceil(N_NODES/256)
#define NBKT 196         // ceil(N_NODES/512) coarse buckets of 512 dst nodes
#define BKT_CAP 10240    // per-bucket capacity (mean 8192 for uniform graph)
#define EPB 8192         // edges per block in k_binA

typedef __attribute__((ext_vector_type(8))) short short8;
typedef __attribute__((ext_vector_type(4))) float floatx4;

// ---- bf16 helpers (RNE) ----
__device__ __forceinline__ unsigned short f2bf(float f) {
  unsigned u = __float_as_uint(f);
  unsigned r = (u + 0x7FFFu + ((u >> 16) & 1u)) >> 16;
  return (unsigned short)r;
}
__device__ __forceinline__ float bf2f(unsigned short h) {
  return __uint_as_float(((unsigned)h) << 16);
}

// ---------------- tiny init ----------------

__global__ __launch_bounds__(256) void k_zero(int* __restrict__ gcur,
                                              int* __restrict__ start) {
  int t = threadIdx.x;
  if (t < NBKT) gcur[t] = 0;
  if (t == 0) start[N_NODES] = N_EDGES;
}

// ---------------- phase A: coarse-bucket edges, clustered writes ----------------

__global__ __launch_bounds__(256) void k_binA(const int* __restrict__ row,
                                              const int* __restrict__ col,
                                              int* __restrict__ gcur,
                                              unsigned int* __restrict__ bktdata) {
  __shared__ int hist[NBKT];
  __shared__ int cur[NBKT];
  __shared__ int gbase[NBKT];
  const int t = threadIdx.x;
  const int e0 = blockIdx.x * EPB;
  const int n = min(EPB, N_EDGES - e0);
  if (t < NBKT) hist[t] = 0;
  __syncthreads();
  for (int i = t; i < n; i += 256) atomicAdd(&hist[col[e0 + i] >> 9], 1);
  __syncthreads();
  if (t < NBKT) {
    cur[t] = 0;
    int h = hist[t];
    gbase[t] = (h > 0) ? atomicAdd(&gcur[t], h) : 0;
  }
  __syncthreads();
  for (int i = t; i < n; i += 256) {
    int c = col[e0 + i];
    int r = row[e0 + i];
    int b = c >> 9;
    int p = atomicAdd(&cur[b], 1);
    bktdata[(size_t)b * BKT_CAP + gbase[b] + p] =
        ((unsigned)(c & 511) << 17) | (unsigned)r;
  }
}

// ---------------- phase B1: per-bucket hist -> dense degi + dis ----------------

__global__ __launch_bounds__(256) void k_histdis(const int* __restrict__ gcur,
                                                 const unsigned int* __restrict__ bktdata,
                                                 int* __restrict__ degi,
                                                 float* __restrict__ dis) {
  __shared__ int h[512];
  const int b = blockIdx.x, t = threadIdx.x;
  h[t] = 0; h[t + 256] = 0;
  __syncthreads();
  const int cnt = gcur[b];
  const unsigned int* p = bktdata + (size_t)b * BKT_CAP;
  for (int i = t; i < cnt; i += 256) atomicAdd(&h[p[i] >> 17], 1);
  __syncthreads();
  int n0 = b * 512 + t;
  if (n0 < N_NODES) { degi[n0] = h[t]; dis[n0] = rsqrtf((float)(h[t] + 1)); }
  int n1 = n0 + 256;
  if (n1 < N_NODES) { degi[n1] = h[t + 256]; dis[n1] = rsqrtf((float)(h[t + 256] + 1)); }
}

// ---------------- scans ----------------

__global__ __launch_bounds__(256) void k_scan1(const int* __restrict__ degi,
                                               int* __restrict__ start,
                                               int* __restrict__ bsum) {
  __shared__ int s[256];
  const int t = threadIdx.x;
  const int i = blockIdx.x * 256 + t;
  int v = (i < N_NODES) ? degi[i] : 0;
  s[t] = v;
  __syncthreads();
#pragma unroll
  for (int off = 1; off < 256; off <<= 1) {
    int u = (t >= off) ? s[t - off] : 0;
    __syncthreads();
    s[t] += u;
    __syncthreads();
  }
  if (i < N_NODES) start[i] = s[t] - v;
  if (t == 255) bsum[blockIdx.x] = s[255];
}

__global__ __launch_bounds__(512) void k_scan2(const int* __restrict__ bsum,
                                               int* __restrict__ bsumS) {
  __shared__ int s[512];
  const int t = threadIdx.x;
  int v = (t < NB_SCAN) ? bsum[t] : 0;
  s[t] = v;
  __syncthreads();
#pragma unroll
  for (int off = 1; off < 512; off <<= 1) {
    int u = (t >= off) ? s[t - off] : 0;
    __syncthreads();
    s[t] += u;
    __syncthreads();
  }
  if (t < NB_SCAN) bsumS[t] = s[t] - v;
}

__global__ __launch_bounds__(256) void k_scan3(int* __restrict__ start,
                                               const int* __restrict__ bsumS) {
  int i = blockIdx.x * 256 + threadIdx.x;
  if (i < N_NODES) start[i] += bsumS[blockIdx.x];
}

// ---------------- phase B2: final placement ----------------

__global__ __launch_bounds__(256) void k_place(const int* __restrict__ gcur,
                                               const unsigned int* __restrict__ bktdata,
                                               const int* __restrict__ start,
                                               int* __restrict__ esrc) {
  __shared__ int cur[512];
  const int b = blockIdx.x, t = threadIdx.x;
  cur[t] = 0; cur[t + 256] = 0;
  __syncthreads();
  const int cnt = gcur[b];
  const unsigned int* p = bktdata + (size_t)b * BKT_CAP;
  const int nbase = b * 512;
  for (int i = t; i < cnt; i += 256) {
    unsigned u = p[i];
    int ld = u >> 17;
    int src = u & 0x1FFFF;
    int pos = start[nbase + ld] + atomicAdd(&cur[ld], 1);
    esrc[pos] = src;
  }
}

// ---------------- GEMM1 (MFMA, persistent): h1b = bf16(dis[row] * (x @ W1)) -----

#define KP 264   // padded k-stride for wt
#define XP 40    // padded k-stride for xs
#define G1_TILES ((N_NODES + 63) / 64)
#define G1_GRID 512

__global__ __launch_bounds__(256) void k_gemm1(const float* __restrict__ x,
                                               const float* __restrict__ W1,
                                               const float* __restrict__ dis,
                                               unsigned short* __restrict__ h1b) {
  __shared__ unsigned short wt[HID * KP];   // wt[n][k] = bf16(W1[k][n])
  __shared__ unsigned short xs[64 * XP];
  const int tid = threadIdx.x;
  const int lane = tid & 63;
  const int w = tid >> 6;
  const int quad = lane >> 4;
  const int l15 = lane & 15;

  // stage W1^T once per block
#pragma unroll
  for (int i = 0; i < 16; ++i) {
    int f = tid + 256 * i;
    int k = f >> 4;
    int n0 = (f & 15) * 4;
    float4 v = *(const float4*)&W1[(size_t)k * HID + n0];
    wt[(n0 + 0) * KP + k] = f2bf(v.x);
    wt[(n0 + 1) * KP + k] = f2bf(v.y);
    wt[(n0 + 2) * KP + k] = f2bf(v.z);
    wt[(n0 + 3) * KP + k] = f2bf(v.w);
  }

  for (int tile = blockIdx.x; tile < G1_TILES; tile += G1_GRID) {
    const int rowBase = tile * 64;
    floatx4 acc[4];
#pragma unroll
    for (int c = 0; c < 4; ++c) acc[c] = (floatx4){0.f, 0.f, 0.f, 0.f};

    for (int kc = 0; kc < F_INDIM; kc += 32) {
#pragma unroll
      for (int i = 0; i < 2; ++i) {
        int f = tid + 256 * i;
        int r = f >> 3;
        int q = f & 7;
        int gr = rowBase + r;
        float4 v = make_float4(0.f, 0.f, 0.f, 0.f);
        if (gr < N_NODES) v = *(const float4*)&x[(size_t)gr * F_INDIM + kc + q * 4];
        ushort4 o;
        o.x = f2bf(v.x); o.y = f2bf(v.y); o.z = f2bf(v.z); o.w = f2bf(v.w);
        *(ushort4*)&xs[r * XP + q * 4] = o;
      }
      __syncthreads();

      const short8 a = *(const short8*)&xs[(w * 16 + l15) * XP + quad * 8];
#pragma unroll
      for (int c = 0; c < 4; ++c) {
        const short8 b = *(const short8*)&wt[(c * 16 + l15) * KP + kc + quad * 8];
        acc[c] = __builtin_amdgcn_mfma_f32_16x16x32_bf16(a, b, acc[c], 0, 0, 0);
      }
      __syncthreads();
    }

#pragma unroll
    for (int reg = 0; reg < 4; ++reg) {
      int gr = rowBase + w * 16 + quad * 4 + reg;
      if (gr < N_NODES) {
        float d = dis[gr];
#pragma unroll
        for (int c = 0; c < 4; ++c)
          h1b[(size_t)gr * HID + c * 16 + l15] = f2bf(d * acc[c][reg]);
      }
    }
  }
}

// ---------------- agg1: ab = bf16(relu(dis[n]*(self+sum) + b1)) ----------------
// one wave per node; 2 edges/wave (half-wave each), dword-packed bf16 gathers.

__global__ __launch_bounds__(256) void k_agg1(const int* __restrict__ esrc,
                                              const int* __restrict__ start,
                                              const float* __restrict__ dis,
                                              const unsigned short* __restrict__ h1b,
                                              const float* __restrict__ b1,
                                              unsigned short* __restrict__ ab) {
  int gid = blockIdx.x * 256 + threadIdx.x;
  int wid = gid >> 6;
  int lane = gid & 63;
  if (wid >= N_NODES) return;
  const int half = lane >> 5;
  const int fl = lane & 31;                 // feature pair: feats 2*fl, 2*fl+1
  const unsigned* hp = (const unsigned*)h1b;
  int s0 = start[wid];
  int cnt = start[wid + 1] - s0;
  int pairs = cnt >> 1;
  float alo = 0.f, ahi = 0.f;
  int i = s0 + half;
  int j = 0;
  for (; j + 8 <= pairs; j += 8, i += 16) {
    int s_[8];
    unsigned u_[8];
#pragma unroll
    for (int k = 0; k < 8; ++k) s_[k] = esrc[i + 2 * k];
#pragma unroll
    for (int k = 0; k < 8; ++k) u_[k] = hp[s_[k] * 32 + fl];
#pragma unroll
    for (int k = 0; k < 8; ++k) {
      alo += __uint_as_float(u_[k] << 16);
      ahi += __uint_as_float(u_[k] & 0xFFFF0000u);
    }
  }
  for (; j < pairs; ++j, i += 2) {
    unsigned u = hp[esrc[i] * 32 + fl];
    alo += __uint_as_float(u << 16);
    ahi += __uint_as_float(u & 0xFFFF0000u);
  }
  if (half == 0 && (cnt & 1)) {
    unsigned u = hp[esrc[s0 + cnt - 1] * 32 + fl];
    alo += __uint_as_float(u << 16);
    ahi += __uint_as_float(u & 0xFFFF0000u);
  }
  // combine halves
  alo += __shfl_xor(alo, 32);
  ahi += __shfl_xor(ahi, 32);
  // self term (pre-scaled), added once on all lanes post-reduction
  unsigned us = hp[wid * 32 + fl];
  alo += __uint_as_float(us << 16);
  ahi += __uint_as_float(us & 0xFFFF0000u);
  float d = dis[wid];
  float2 bv = ((const float2*)b1)[fl];
  float vlo = fmaxf(d * alo + bv.x, 0.f);
  float vhi = fmaxf(d * ahi + bv.y, 0.f);
  if (half == 0) {
    unsigned o = (unsigned)f2bf(vlo) | ((unsigned)f2bf(vhi) << 16);
    ((unsigned*)ab)[wid * 32 + fl] = o;
  }
}

// ---------------- GEMM2 (MFMA): gb = bf16(dis[row] * (ab @ W2)), rows padded 64 ----

#define AP 72    // padded k-stride

__global__ __launch_bounds__(256) void k_gemm2(const unsigned short* __restrict__ ab,
                                               const float* __restrict__ W2,
                                               const float* __restrict__ dis,
                                               unsigned short* __restrict__ gb) {
  __shared__ unsigned short as[64 * AP];
  __shared__ unsigned short w2t[48 * AP];   // w2t[n][k] = bf16(W2[k][n]), 0-pad n>=40
  const int tid = threadIdx.x;
  const int lane = tid & 63;
  const int w = tid >> 6;
  const int quad = lane >> 4;
  const int l15 = lane & 15;
  const int rowBase = blockIdx.x * 64;

  for (int i = tid; i < 48 * 64; i += 256) {
    int n = i >> 6;
    int k = i & 63;
    w2t[n * AP + k] = (n < NCLS) ? f2bf(W2[(size_t)k * NCLS + n]) : (unsigned short)0;
  }
#pragma unroll
  for (int i = 0; i < 2; ++i) {
    int f = tid + 256 * i;
    int r = f >> 3;
    int q = f & 7;
    int gr = rowBase + r;
    short8 v = (short8){0, 0, 0, 0, 0, 0, 0, 0};
    if (gr < N_NODES) v = *(const short8*)&ab[(size_t)gr * HID + q * 8];
    *(short8*)&as[r * AP + q * 8] = v;
  }
  __syncthreads();

  floatx4 acc[3];
#pragma unroll
  for (int c = 0; c < 3; ++c) acc[c] = (floatx4){0.f, 0.f, 0.f, 0.f};

#pragma unroll
  for (int kh = 0; kh < 2; ++kh) {
    const short8 a = *(const short8*)&as[(w * 16 + l15) * AP + kh * 32 + quad * 8];
#pragma unroll
    for (int c = 0; c < 3; ++c) {
      const short8 b = *(const short8*)&w2t[(c * 16 + l15) * AP + kh * 32 + quad * 8];
      acc[c] = __builtin_amdgcn_mfma_f32_16x16x32_bf16(a, b, acc[c], 0, 0, 0);
    }
  }

#pragma unroll
  for (int reg = 0; reg < 4; ++reg) {
    int gr = rowBase + w * 16 + quad * 4 + reg;
    if (gr < N_NODES) {
      float d = dis[gr];
#pragma unroll
      for (int c = 0; c < 3; ++c) {
        int cc = c * 16 + l15;   // < 48; cols 40..47 are zero-padded
        gb[(size_t)gr * 64 + cc] = f2bf(d * acc[c][reg]);
      }
    }
  }
}

// ---------------- agg2 + log_softmax fused: 2 edges/wave, packed ----------------

__global__ __launch_bounds__(256) void k_agg2ls(const int* __restrict__ esrc,
                                                const int* __restrict__ start,
                                                const float* __restrict__ dis,
                                                const unsigned short* __restrict__ gb,
                                                const float* __restrict__ b2,
                                                float* __restrict__ out) {
  int gid = blockIdx.x * 256 + threadIdx.x;
  int node = gid >> 6;
  int lane = gid & 63;
  if (node >= N_NODES) return;
  const int half = lane >> 5;
  const int fl = lane & 31;                 // class pair 2*fl, 2*fl+1
  const bool act = fl < (NCLS / 2);         // fl < 20
  const unsigned* gp = (const unsigned*)gb;
  int s0 = start[node];
  int cnt = start[node + 1] - s0;
  int pairs = cnt >> 1;
  float alo = 0.f, ahi = 0.f;
  int i = s0 + half;
  int j = 0;
  for (; j + 8 <= pairs; j += 8, i += 16) {
    int s_[8];
    unsigned u_[8];
#pragma unroll
    for (int k = 0; k < 8; ++k) s_[k] = esrc[i + 2 * k];
#pragma unroll
    for (int k = 0; k < 8; ++k) u_[k] = gp[s_[k] * 32 + fl];
#pragma unroll
    for (int k = 0; k < 8; ++k) {
      alo += __uint_as_float(u_[k] << 16);
      ahi += __uint_as_float(u_[k] & 0xFFFF0000u);
    }
  }
  for (; j < pairs; ++j, i += 2) {
    unsigned u = gp[esrc[i] * 32 + fl];
    alo += __uint_as_float(u << 16);
    ahi += __uint_as_float(u & 0xFFFF0000u);
  }
  if (half == 0 && (cnt & 1)) {
    unsigned u = gp[esrc[s0 + cnt - 1] * 32 + fl];
    alo += __uint_as_float(u << 16);
    ahi += __uint_as_float(u & 0xFFFF0000u);
  }
  alo += __shfl_xor(alo, 32);
  ahi += __shfl_xor(ahi, 32);
  unsigned us = gp[node * 32 + fl];   // self (pre-scaled); cols>=40 are zeros
  alo += __uint_as_float(us << 16);
  ahi += __uint_as_float(us & 0xFFFF0000u);
  float d = dis[node];
  float vlo = 0.f, vhi = 0.f;
  if (act) {
    float2 bv = ((const float2*)b2)[fl];
    vlo = d * alo + bv.x;
    vhi = d * ahi + bv.y;
  }
  // log_softmax over 40 classes stored as 20 lane-pairs (duplicated across halves)
  float m = act ? fmaxf(vlo, vhi) : -INFINITY;
#pragma unroll
  for (int off = 32; off > 0; off >>= 1) m = fmaxf(m, __shfl_xor(m, off));
  float el = (act && half == 0) ? (__expf(vlo - m) + __expf(vhi - m)) : 0.f;
#pragma unroll
  for (int off = 32; off > 0; off >>= 1) el += __shfl_xor(el, off);
  float ls = logf(el);
  if (act && half == 0) {
    float2 o = make_float2(vlo - m - ls, vhi - m - ls);
    *(float2*)&out[(size_t)node * NCLS + fl * 2] = o;
  }
}

// ---------------- launch ----------------

extern "C" void kernel_launch(void* const* d_in, const int* in_sizes, int n_in,
                              void* d_out, int out_size, void* d_ws, size_t ws_size,
                              hipStream_t stream) {
  const float* x  = (const float*)d_in[0];
  const int*   ei = (const int*)d_in[1];
  const float* W1 = (const float*)d_in[2];
  const float* b1 = (const float*)d_in[3];
  const float* W2 = (const float*)d_in[4];
  const float* b2 = (const float*)d_in[5];
  float* out = (float*)d_out;

  const int* row = ei;             // edge_index[0] = src
  const int* col = ei + N_EDGES;   // edge_index[1] = dst

  // workspace layout (~41 MB)
  int*            esrc    = (int*)d_ws;                            // E ints     (6.4 MB)
  unsigned int*   bktdata = (unsigned int*)(esrc + N_EDGES);       // NBKT*CAP   (8.0 MB)
  unsigned short* h1b     = (unsigned short*)(bktdata + (size_t)NBKT * BKT_CAP); // 12.8 MB
  unsigned short* ab      = h1b + (size_t)N_NODES * HID;           // N*64 bf16  (12.8 MB)
  float*          dis     = (float*)(ab + (size_t)N_NODES * HID);  // N
  int*            degi    = (int*)(dis + N_NODES);                 // N
  int*            start   = degi + N_NODES;                        // N+1
  int*            gcur    = start + N_NODES + 1;                   // NBKT
  int*            bsum    = gcur + NBKT;                           // NB_SCAN
  int*            bsumS   = bsum + NB_SCAN;                        // NB_SCAN
  unsigned short* gb      = h1b;                                   // N*64 bf16, reuse

  k_zero<<<1, 256, 0, stream>>>(gcur, start);
  k_binA<<<(N_EDGES + EPB - 1) / EPB, 256, 0, stream>>>(row, col, gcur, bktdata);
  k_histdis<<<NBKT, 256, 0, stream>>>(gcur, bktdata, degi, dis);
  k_scan1<<<NB_SCAN, 256, 0, stream>>>(degi, start, bsum);
  k_scan2<<<1, 512, 0, stream>>>(bsum, bsumS);
  k_scan3<<<NB_SCAN, 256, 0, stream>>>(start, bsumS);
  k_place<<<NBKT, 256, 0, stream>>>(gcur, bktdata, start, esrc);

  k_gemm1<<<G1_GRID, 256, 0, stream>>>(x, W1, dis, h1b);
  k_agg1<<<(N_NODES * 64 + 255) / 256, 256, 0, stream>>>(esrc, start, dis, h1b, b1, ab);

  k_gemm2<<<(N_NODES + 63) / 64, 256, 0, stream>>>(ab, W2, dis, gb);
  k_agg2ls<<<(N_NODES * 64 + 255) / 256, 256, 0, stream>>>(esrc, start, dis, gb, b2, out);
}

// Round 8
// 392.900 us; speedup vs baseline: 1.0419x; 1.0419x over previous
//
#include <hip/hip_runtime.h>
#include <math.h>

#define N_NODES 100000
#define N_EDGES 1600000
#define F_INDIM 256
#define HID 64
#define NCLS 40
#define NB_SCAN 391      // ceil(N_NODES/256)
#define NBKT 196         // ceil(N_NODES/512) coarse buckets of 512 dst nodes
#define BKT_CAP 10240    // per-bucket capacity (mean 8192 for uniform graph)
#define EPB 8192         // edges per block in k_binA

typedef __attribute__((ext_vector_type(8))) short short8;
typedef __attribute__((ext_vector_type(4))) float floatx4;

// ---- bf16 helpers (RNE) ----
__device__ __forceinline__ unsigned short f2bf(float f) {
  unsigned u = __float_as_uint(f);
  unsigned r = (u + 0x7FFFu + ((u >> 16) & 1u)) >> 16;
  return (unsigned short)r;
}
__device__ __forceinline__ float bf2f(unsigned short h) {
  return __uint_as_float(((unsigned)h) << 16);
}

// ---------------- tiny init ----------------

__global__ __launch_bounds__(256) void k_zero(int* __restrict__ gcur,
                                              int* __restrict__ start) {
  int t = threadIdx.x;
  if (t < NBKT) gcur[t] = 0;
  if (t == 0) start[N_NODES] = N_EDGES;
}

// ---------------- phase A: coarse-bucket edges, clustered writes ----------------

__global__ __launch_bounds__(256) void k_binA(const int* __restrict__ row,
                                              const int* __restrict__ col,
                                              int* __restrict__ gcur,
                                              unsigned int* __restrict__ bktdata) {
  __shared__ int hist[NBKT];
  __shared__ int cur[NBKT];
  __shared__ int gbase[NBKT];
  const int t = threadIdx.x;
  const int e0 = blockIdx.x * EPB;
  const int n = min(EPB, N_EDGES - e0);
  if (t < NBKT) hist[t] = 0;
  __syncthreads();
  for (int i = t; i < n; i += 256) atomicAdd(&hist[col[e0 + i] >> 9], 1);
  __syncthreads();
  if (t < NBKT) {
    cur[t] = 0;
    int h = hist[t];
    gbase[t] = (h > 0) ? atomicAdd(&gcur[t], h) : 0;
  }
  __syncthreads();
  for (int i = t; i < n; i += 256) {
    int c = col[e0 + i];
    int r = row[e0 + i];
    int b = c >> 9;
    int p = atomicAdd(&cur[b], 1);
    bktdata[(size_t)b * BKT_CAP + gbase[b] + p] =
        ((unsigned)(c & 511) << 17) | (unsigned)r;
  }
}

// ---------------- phase B1: per-bucket hist -> dense degi + dis ----------------

__global__ __launch_bounds__(256) void k_histdis(const int* __restrict__ gcur,
                                                 const unsigned int* __restrict__ bktdata,
                                                 int* __restrict__ degi,
                                                 float* __restrict__ dis) {
  __shared__ int h[512];
  const int b = blockIdx.x, t = threadIdx.x;
  h[t] = 0; h[t + 256] = 0;
  __syncthreads();
  const int cnt = gcur[b];
  const unsigned int* p = bktdata + (size_t)b * BKT_CAP;
  for (int i = t; i < cnt; i += 256) atomicAdd(&h[p[i] >> 17], 1);
  __syncthreads();
  int n0 = b * 512 + t;
  if (n0 < N_NODES) { degi[n0] = h[t]; dis[n0] = rsqrtf((float)(h[t] + 1)); }
  int n1 = n0 + 256;
  if (n1 < N_NODES) { degi[n1] = h[t + 256]; dis[n1] = rsqrtf((float)(h[t + 256] + 1)); }
}

// ---------------- scans ----------------

__global__ __launch_bounds__(256) void k_scan1(const int* __restrict__ degi,
                                               int* __restrict__ start,
                                               int* __restrict__ bsum) {
  __shared__ int s[256];
  const int t = threadIdx.x;
  const int i = blockIdx.x * 256 + t;
  int v = (i < N_NODES) ? degi[i] : 0;
  s[t] = v;
  __syncthreads();
#pragma unroll
  for (int off = 1; off < 256; off <<= 1) {
    int u = (t >= off) ? s[t - off] : 0;
    __syncthreads();
    s[t] += u;
    __syncthreads();
  }
  if (i < N_NODES) start[i] = s[t] - v;
  if (t == 255) bsum[blockIdx.x] = s[255];
}

__global__ __launch_bounds__(512) void k_scan2(const int* __restrict__ bsum,
                                               int* __restrict__ bsumS) {
  __shared__ int s[512];
  const int t = threadIdx.x;
  int v = (t < NB_SCAN) ? bsum[t] : 0;
  s[t] = v;
  __syncthreads();
#pragma unroll
  for (int off = 1; off < 512; off <<= 1) {
    int u = (t >= off) ? s[t - off] : 0;
    __syncthreads();
    s[t] += u;
    __syncthreads();
  }
  if (t < NB_SCAN) bsumS[t] = s[t] - v;
}

__global__ __launch_bounds__(256) void k_scan3(int* __restrict__ start,
                                               const int* __restrict__ bsumS) {
  int i = blockIdx.x * 256 + threadIdx.x;
  if (i < N_NODES) start[i] += bsumS[blockIdx.x];
}

// ---------------- phase B2: final placement ----------------

__global__ __launch_bounds__(256) void k_place(const int* __restrict__ gcur,
                                               const unsigned int* __restrict__ bktdata,
                                               const int* __restrict__ start,
                                               int* __restrict__ esrc) {
  __shared__ int cur[512];
  const int b = blockIdx.x, t = threadIdx.x;
  cur[t] = 0; cur[t + 256] = 0;
  __syncthreads();
  const int cnt = gcur[b];
  const unsigned int* p = bktdata + (size_t)b * BKT_CAP;
  const int nbase = b * 512;
  for (int i = t; i < cnt; i += 256) {
    unsigned u = p[i];
    int ld = u >> 17;
    int src = u & 0x1FFFF;
    int pos = start[nbase + ld] + atomicAdd(&cur[ld], 1);
    esrc[pos] = src;
  }
}

// ---------------- GEMM1 (MFMA): h1b = bf16(dis[row] * (x @ W1)) ----------------
// 64 rows/block, 4 waves x 16 rows. A-fragments loaded DIRECTLY from global
// (x has zero cross-block reuse -> LDS staging was pure overhead); W1^T staged
// to LDS once (bf16), single barrier, fully-unrolled K-loop.

#define KP 264   // padded k-stride for wt (2-way bank aliasing only = free)

__global__ __launch_bounds__(256) void k_gemm1(const float* __restrict__ x,
                                               const float* __restrict__ W1,
                                               const float* __restrict__ dis,
                                               unsigned short* __restrict__ h1b) {
  __shared__ unsigned short wt[HID * KP];   // wt[n][k] = bf16(W1[k][n])
  const int tid = threadIdx.x;
  const int lane = tid & 63;
  const int w = tid >> 6;
  const int quad = lane >> 4;
  const int l15 = lane & 15;
  const int rowBase = blockIdx.x * 64;

  // stage W1^T once
#pragma unroll
  for (int i = 0; i < 16; ++i) {
    int f = tid + 256 * i;
    int k = f >> 4;
    int n0 = (f & 15) * 4;
    float4 v = *(const float4*)&W1[(size_t)k * HID + n0];
    wt[(n0 + 0) * KP + k] = f2bf(v.x);
    wt[(n0 + 1) * KP + k] = f2bf(v.y);
    wt[(n0 + 2) * KP + k] = f2bf(v.z);
    wt[(n0 + 3) * KP + k] = f2bf(v.w);
  }
  __syncthreads();

  // this lane's A row (clamped; bad rows' results discarded at store)
  const int ar = rowBase + w * 16 + l15;
  const float* xrow = x + (size_t)((ar < N_NODES) ? ar : N_NODES - 1) * F_INDIM + quad * 8;

  floatx4 acc[4];
#pragma unroll
  for (int c = 0; c < 4; ++c) acc[c] = (floatx4){0.f, 0.f, 0.f, 0.f};

#pragma unroll
  for (int kc = 0; kc < F_INDIM; kc += 32) {
    const float4 va = *(const float4*)(xrow + kc);
    const float4 vb = *(const float4*)(xrow + kc + 4);
    short8 a;
    a[0] = (short)f2bf(va.x); a[1] = (short)f2bf(va.y);
    a[2] = (short)f2bf(va.z); a[3] = (short)f2bf(va.w);
    a[4] = (short)f2bf(vb.x); a[5] = (short)f2bf(vb.y);
    a[6] = (short)f2bf(vb.z); a[7] = (short)f2bf(vb.w);
#pragma unroll
    for (int c = 0; c < 4; ++c) {
      const short8 b = *(const short8*)&wt[(c * 16 + l15) * KP + kc + quad * 8];
      acc[c] = __builtin_amdgcn_mfma_f32_16x16x32_bf16(a, b, acc[c], 0, 0, 0);
    }
  }

  // epilogue: C/D layout col=lane&15, row=quad*4+reg
#pragma unroll
  for (int reg = 0; reg < 4; ++reg) {
    int gr = rowBase + w * 16 + quad * 4 + reg;
    if (gr < N_NODES) {
      float d = dis[gr];
#pragma unroll
      for (int c = 0; c < 4; ++c)
        h1b[(size_t)gr * HID + c * 16 + l15] = f2bf(d * acc[c][reg]);
    }
  }
}

// ---------------- agg1: ab = bf16(relu(dis[n]*(self+sum) + b1)) ----------------
// one wave per node; 2 edges/wave (half-wave each), dword-packed bf16 gathers.

__global__ __launch_bounds__(256) void k_agg1(const int* __restrict__ esrc,
                                              const int* __restrict__ start,
                                              const float* __restrict__ dis,
                                              const unsigned short* __restrict__ h1b,
                                              const float* __restrict__ b1,
                                              unsigned short* __restrict__ ab) {
  int gid = blockIdx.x * 256 + threadIdx.x;
  int wid = gid >> 6;
  int lane = gid & 63;
  if (wid >= N_NODES) return;
  const int half = lane >> 5;
  const int fl = lane & 31;                 // feature pair: feats 2*fl, 2*fl+1
  const unsigned* hp = (const unsigned*)h1b;
  int s0 = start[wid];
  int cnt = start[wid + 1] - s0;
  int pairs = cnt >> 1;
  float alo = 0.f, ahi = 0.f;
  int i = s0 + half;
  int j = 0;
  for (; j + 8 <= pairs; j += 8, i += 16) {
    int s_[8];
    unsigned u_[8];
#pragma unroll
    for (int k = 0; k < 8; ++k) s_[k] = esrc[i + 2 * k];
#pragma unroll
    for (int k = 0; k < 8; ++k) u_[k] = hp[s_[k] * 32 + fl];
#pragma unroll
    for (int k = 0; k < 8; ++k) {
      alo += __uint_as_float(u_[k] << 16);
      ahi += __uint_as_float(u_[k] & 0xFFFF0000u);
    }
  }
  for (; j < pairs; ++j, i += 2) {
    unsigned u = hp[esrc[i] * 32 + fl];
    alo += __uint_as_float(u << 16);
    ahi += __uint_as_float(u & 0xFFFF0000u);
  }
  if (half == 0 && (cnt & 1)) {
    unsigned u = hp[esrc[s0 + cnt - 1] * 32 + fl];
    alo += __uint_as_float(u << 16);
    ahi += __uint_as_float(u & 0xFFFF0000u);
  }
  // combine halves
  alo += __shfl_xor(alo, 32);
  ahi += __shfl_xor(ahi, 32);
  // self term (pre-scaled), added once post-reduction
  unsigned us = hp[wid * 32 + fl];
  alo += __uint_as_float(us << 16);
  ahi += __uint_as_float(us & 0xFFFF0000u);
  float d = dis[wid];
  float2 bv = ((const float2*)b1)[fl];
  float vlo = fmaxf(d * alo + bv.x, 0.f);
  float vhi = fmaxf(d * ahi + bv.y, 0.f);
  if (half == 0) {
    unsigned o = (unsigned)f2bf(vlo) | ((unsigned)f2bf(vhi) << 16);
    ((unsigned*)ab)[wid * 32 + fl] = o;
  }
}

// ---------------- GEMM2 (MFMA): gb = bf16(dis[row] * (ab @ W2)), rows padded 64 ----

#define AP 72    // padded k-stride

__global__ __launch_bounds__(256) void k_gemm2(const unsigned short* __restrict__ ab,
                                               const float* __restrict__ W2,
                                               const float* __restrict__ dis,
                                               unsigned short* __restrict__ gb) {
  __shared__ unsigned short as[64 * AP];
  __shared__ unsigned short w2t[48 * AP];   // w2t[n][k] = bf16(W2[k][n]), 0-pad n>=40
  const int tid = threadIdx.x;
  const int lane = tid & 63;
  const int w = tid >> 6;
  const int quad = lane >> 4;
  const int l15 = lane & 15;
  const int rowBase = blockIdx.x * 64;

  for (int i = tid; i < 48 * 64; i += 256) {
    int n = i >> 6;
    int k = i & 63;
    w2t[n * AP + k] = (n < NCLS) ? f2bf(W2[(size_t)k * NCLS + n]) : (unsigned short)0;
  }
#pragma unroll
  for (int i = 0; i < 2; ++i) {
    int f = tid + 256 * i;
    int r = f >> 3;
    int q = f & 7;
    int gr = rowBase + r;
    short8 v = (short8){0, 0, 0, 0, 0, 0, 0, 0};
    if (gr < N_NODES) v = *(const short8*)&ab[(size_t)gr * HID + q * 8];
    *(short8*)&as[r * AP + q * 8] = v;
  }
  __syncthreads();

  floatx4 acc[3];
#pragma unroll
  for (int c = 0; c < 3; ++c) acc[c] = (floatx4){0.f, 0.f, 0.f, 0.f};

#pragma unroll
  for (int kh = 0; kh < 2; ++kh) {
    const short8 a = *(const short8*)&as[(w * 16 + l15) * AP + kh * 32 + quad * 8];
#pragma unroll
    for (int c = 0; c < 3; ++c) {
      const short8 b = *(const short8*)&w2t[(c * 16 + l15) * AP + kh * 32 + quad * 8];
      acc[c] = __builtin_amdgcn_mfma_f32_16x16x32_bf16(a, b, acc[c], 0, 0, 0);
    }
  }

#pragma unroll
  for (int reg = 0; reg < 4; ++reg) {
    int gr = rowBase + w * 16 + quad * 4 + reg;
    if (gr < N_NODES) {
      float d = dis[gr];
#pragma unroll
      for (int c = 0; c < 3; ++c) {
        int cc = c * 16 + l15;   // < 48; cols 40..47 are zero-padded
        gb[(size_t)gr * 64 + cc] = f2bf(d * acc[c][reg]);
      }
    }
  }
}

// ---------------- agg2 + log_softmax fused: 2 edges/wave, packed ----------------

__global__ __launch_bounds__(256) void k_agg2ls(const int* __restrict__ esrc,
                                                const int* __restrict__ start,
                                                const float* __restrict__ dis,
                                                const unsigned short* __restrict__ gb,
                                                const float* __restrict__ b2,
                                                float* __restrict__ out) {
  int gid = blockIdx.x * 256 + threadIdx.x;
  int node = gid >> 6;
  int lane = gid & 63;
  if (node >= N_NODES) return;
  const int half = lane >> 5;
  const int fl = lane & 31;                 // class pair 2*fl, 2*fl+1
  const bool act = fl < (NCLS / 2);         // fl < 20
  const unsigned* gp = (const unsigned*)gb;
  int s0 = start[node];
  int cnt = start[node + 1] - s0;
  int pairs = cnt >> 1;
  float alo = 0.f, ahi = 0.f;
  int i = s0 + half;
  int j = 0;
  for (; j + 8 <= pairs; j += 8, i += 16) {
    int s_[8];
    unsigned u_[8];
#pragma unroll
    for (int k = 0; k < 8; ++k) s_[k] = esrc[i + 2 * k];
#pragma unroll
    for (int k = 0; k < 8; ++k) u_[k] = gp[s_[k] * 32 + fl];
#pragma unroll
    for (int k = 0; k < 8; ++k) {
      alo += __uint_as_float(u_[k] << 16);
      ahi += __uint_as_float(u_[k] & 0xFFFF0000u);
    }
  }
  for (; j < pairs; ++j, i += 2) {
    unsigned u = gp[esrc[i] * 32 + fl];
    alo += __uint_as_float(u << 16);
    ahi += __uint_as_float(u & 0xFFFF0000u);
  }
  if (half == 0 && (cnt & 1)) {
    unsigned u = gp[esrc[s0 + cnt - 1] * 32 + fl];
    alo += __uint_as_float(u << 16);
    ahi += __uint_as_float(u & 0xFFFF0000u);
  }
  alo += __shfl_xor(alo, 32);
  ahi += __shfl_xor(ahi, 32);
  unsigned us = gp[node * 32 + fl];   // self (pre-scaled); cols>=40 are zeros
  alo += __uint_as_float(us << 16);
  ahi += __uint_as_float(us & 0xFFFF0000u);
  float d = dis[node];
  float vlo = 0.f, vhi = 0.f;
  if (act) {
    float2 bv = ((const float2*)b2)[fl];
    vlo = d * alo + bv.x;
    vhi = d * ahi + bv.y;
  }
  float m = act ? fmaxf(vlo, vhi) : -INFINITY;
#pragma unroll
  for (int off = 32; off > 0; off >>= 1) m = fmaxf(m, __shfl_xor(m, off));
  float el = (act && half == 0) ? (__expf(vlo - m) + __expf(vhi - m)) : 0.f;
#pragma unroll
  for (int off = 32; off > 0; off >>= 1) el += __shfl_xor(el, off);
  float ls = logf(el);
  if (act && half == 0) {
    float2 o = make_float2(vlo - m - ls, vhi - m - ls);
    *(float2*)&out[(size_t)node * NCLS + fl * 2] = o;
  }
}

// ---------------- launch ----------------

extern "C" void kernel_launch(void* const* d_in, const int* in_sizes, int n_in,
                              void* d_out, int out_size, void* d_ws, size_t ws_size,
                              hipStream_t stream) {
  const float* x  = (const float*)d_in[0];
  const int*   ei = (const int*)d_in[1];
  const float* W1 = (const float*)d_in[2];
  const float* b1 = (const float*)d_in[3];
  const float* W2 = (const float*)d_in[4];
  const float* b2 = (const float*)d_in[5];
  float* out = (float*)d_out;

  const int* row = ei;             // edge_index[0] = src
  const int* col = ei + N_EDGES;   // edge_index[1] = dst

  // workspace layout (~41 MB)
  int*            esrc    = (int*)d_ws;                            // E ints     (6.4 MB)
  unsigned int*   bktdata = (unsigned int*)(esrc + N_EDGES);       // NBKT*CAP   (8.0 MB)
  unsigned short* h1b     = (unsigned short*)(bktdata + (size_t)NBKT * BKT_CAP); // 12.8 MB
  unsigned short* ab      = h1b + (size_t)N_NODES * HID;           // N*64 bf16  (12.8 MB)
  float*          dis     = (float*)(ab + (size_t)N_NODES * HID);  // N
  int*            degi    = (int*)(dis + N_NODES);                 // N
  int*            start   = degi + N_NODES;                        // N+1
  int*            gcur    = start + N_NODES + 1;                   // NBKT
  int*            bsum    = gcur + NBKT;                           // NB_SCAN
  int*            bsumS   = bsum + NB_SCAN;                        // NB_SCAN
  unsigned short* gb      = h1b;                                   // N*64 bf16, reuse

  k_zero<<<1, 256, 0, stream>>>(gcur, start);
  k_binA<<<(N_EDGES + EPB - 1) / EPB, 256, 0, stream>>>(row, col, gcur, bktdata);
  k_histdis<<<NBKT, 256, 0, stream>>>(gcur, bktdata, degi, dis);
  k_scan1<<<NB_SCAN, 256, 0, stream>>>(degi, start, bsum);
  k_scan2<<<1, 512, 0, stream>>>(bsum, bsumS);
  k_scan3<<<NB_SCAN, 256, 0, stream>>>(start, bsumS);
  k_place<<<NBKT, 256, 0, stream>>>(gcur, bktdata, start, esrc);

  k_gemm1<<<(N_NODES + 63) / 64, 256, 0, stream>>>(x, W1, dis, h1b);
  k_agg1<<<(N_NODES * 64 + 255) / 256, 256, 0, stream>>>(esrc, start, dis, h1b, b1, ab);

  k_gemm2<<<(N_NODES + 63) / 64, 256, 0, stream>>>(ab, W2, dis, gb);
  k_agg2ls<<<(N_NODES * 64 + 255) / 256, 256, 0, stream>>>(esrc, start, dis, gb, b2, out);
}

// Round 9
// 356.771 us; speedup vs baseline: 1.1474x; 1.1013x over previous
//
#include <hip/hip_runtime.h>
#include <math.h>

#define N_NODES 100000
#define N_EDGES 1600000
#define F_INDIM 256
#define HID 64
#define NCLS 40
#define NB_SCAN 391      // ceil(N_NODES/256)
#define NBKT 196         // ceil(N_NODES/512) coarse buckets of 512 dst nodes
#define BKT_CAP 10240    // per-bucket capacity (mean 8192 for uniform graph)
#define EPB 8192         // edges per block in k_binA

typedef __attribute__((ext_vector_type(8))) short short8;
typedef __attribute__((ext_vector_type(4))) float floatx4;

// ---- bf16 helpers (RNE) ----
__device__ __forceinline__ unsigned short f2bf(float f) {
  unsigned u = __float_as_uint(f);
  unsigned r = (u + 0x7FFFu + ((u >> 16) & 1u)) >> 16;
  return (unsigned short)r;
}
__device__ __forceinline__ float bf2f(unsigned short h) {
  return __uint_as_float(((unsigned)h) << 16);
}
// accumulate 8 packed bf16 (one 16B quad of a row) into 8 fp32 accumulators
__device__ __forceinline__ void add8(float* a, uint4 u) {
  a[0] += __uint_as_float(u.x << 16);
  a[1] += __uint_as_float(u.x & 0xFFFF0000u);
  a[2] += __uint_as_float(u.y << 16);
  a[3] += __uint_as_float(u.y & 0xFFFF0000u);
  a[4] += __uint_as_float(u.z << 16);
  a[5] += __uint_as_float(u.z & 0xFFFF0000u);
  a[6] += __uint_as_float(u.w << 16);
  a[7] += __uint_as_float(u.w & 0xFFFF0000u);
}

// ---------------- tiny init ----------------

__global__ __launch_bounds__(256) void k_zero(int* __restrict__ gcur,
                                              int* __restrict__ start) {
  int t = threadIdx.x;
  if (t < NBKT) gcur[t] = 0;
  if (t == 0) start[N_NODES] = N_EDGES;
}

// ---------------- phase A: coarse-bucket edges, clustered writes ----------------

__global__ __launch_bounds__(256) void k_binA(const int* __restrict__ row,
                                              const int* __restrict__ col,
                                              int* __restrict__ gcur,
                                              unsigned int* __restrict__ bktdata) {
  __shared__ int hist[NBKT];
  __shared__ int cur[NBKT];
  __shared__ int gbase[NBKT];
  const int t = threadIdx.x;
  const int e0 = blockIdx.x * EPB;
  const int n = min(EPB, N_EDGES - e0);
  if (t < NBKT) hist[t] = 0;
  __syncthreads();
  for (int i = t; i < n; i += 256) atomicAdd(&hist[col[e0 + i] >> 9], 1);
  __syncthreads();
  if (t < NBKT) {
    cur[t] = 0;
    int h = hist[t];
    gbase[t] = (h > 0) ? atomicAdd(&gcur[t], h) : 0;
  }
  __syncthreads();
  for (int i = t; i < n; i += 256) {
    int c = col[e0 + i];
    int r = row[e0 + i];
    int b = c >> 9;
    int p = atomicAdd(&cur[b], 1);
    bktdata[(size_t)b * BKT_CAP + gbase[b] + p] =
        ((unsigned)(c & 511) << 17) | (unsigned)r;
  }
}

// ---------------- phase B1: per-bucket hist -> dense degi + dis ----------------

__global__ __launch_bounds__(256) void k_histdis(const int* __restrict__ gcur,
                                                 const unsigned int* __restrict__ bktdata,
                                                 int* __restrict__ degi,
                                                 float* __restrict__ dis) {
  __shared__ int h[512];
  const int b = blockIdx.x, t = threadIdx.x;
  h[t] = 0; h[t + 256] = 0;
  __syncthreads();
  const int cnt = gcur[b];
  const unsigned int* p = bktdata + (size_t)b * BKT_CAP;
  for (int i = t; i < cnt; i += 256) atomicAdd(&h[p[i] >> 17], 1);
  __syncthreads();
  int n0 = b * 512 + t;
  if (n0 < N_NODES) { degi[n0] = h[t]; dis[n0] = rsqrtf((float)(h[t] + 1)); }
  int n1 = n0 + 256;
  if (n1 < N_NODES) { degi[n1] = h[t + 256]; dis[n1] = rsqrtf((float)(h[t + 256] + 1)); }
}

// ---------------- scans ----------------

__global__ __launch_bounds__(256) void k_scan1(const int* __restrict__ degi,
                                               int* __restrict__ start,
                                               int* __restrict__ bsum) {
  __shared__ int s[256];
  const int t = threadIdx.x;
  const int i = blockIdx.x * 256 + t;
  int v = (i < N_NODES) ? degi[i] : 0;
  s[t] = v;
  __syncthreads();
#pragma unroll
  for (int off = 1; off < 256; off <<= 1) {
    int u = (t >= off) ? s[t - off] : 0;
    __syncthreads();
    s[t] += u;
    __syncthreads();
  }
  if (i < N_NODES) start[i] = s[t] - v;
  if (t == 255) bsum[blockIdx.x] = s[255];
}

__global__ __launch_bounds__(512) void k_scan2(const int* __restrict__ bsum,
                                               int* __restrict__ bsumS) {
  __shared__ int s[512];
  const int t = threadIdx.x;
  int v = (t < NB_SCAN) ? bsum[t] : 0;
  s[t] = v;
  __syncthreads();
#pragma unroll
  for (int off = 1; off < 512; off <<= 1) {
    int u = (t >= off) ? s[t - off] : 0;
    __syncthreads();
    s[t] += u;
    __syncthreads();
  }
  if (t < NB_SCAN) bsumS[t] = s[t] - v;
}

__global__ __launch_bounds__(256) void k_scan3(int* __restrict__ start,
                                               const int* __restrict__ bsumS) {
  int i = blockIdx.x * 256 + threadIdx.x;
  if (i < N_NODES) start[i] += bsumS[blockIdx.x];
}

// ---------------- phase B2: final placement ----------------

__global__ __launch_bounds__(256) void k_place(const int* __restrict__ gcur,
                                               const unsigned int* __restrict__ bktdata,
                                               const int* __restrict__ start,
                                               int* __restrict__ esrc) {
  __shared__ int cur[512];
  const int b = blockIdx.x, t = threadIdx.x;
  cur[t] = 0; cur[t + 256] = 0;
  __syncthreads();
  const int cnt = gcur[b];
  const unsigned int* p = bktdata + (size_t)b * BKT_CAP;
  const int nbase = b * 512;
  for (int i = t; i < cnt; i += 256) {
    unsigned u = p[i];
    int ld = u >> 17;
    int src = u & 0x1FFFF;
    int pos = start[nbase + ld] + atomicAdd(&cur[ld], 1);
    esrc[pos] = src;
  }
}

// ---------------- GEMM1 (MFMA): h1b = bf16(dis[row] * (x @ W1)) ----------------
// A-fragments direct from global (x has zero cross-block reuse); W1^T in LDS.

#define KP 264   // padded k-stride for wt (2-way bank aliasing only = free)

__global__ __launch_bounds__(256) void k_gemm1(const float* __restrict__ x,
                                               const float* __restrict__ W1,
                                               const float* __restrict__ dis,
                                               unsigned short* __restrict__ h1b) {
  __shared__ unsigned short wt[HID * KP];   // wt[n][k] = bf16(W1[k][n])
  const int tid = threadIdx.x;
  const int lane = tid & 63;
  const int w = tid >> 6;
  const int quad = lane >> 4;
  const int l15 = lane & 15;
  const int rowBase = blockIdx.x * 64;

#pragma unroll
  for (int i = 0; i < 16; ++i) {
    int f = tid + 256 * i;
    int k = f >> 4;
    int n0 = (f & 15) * 4;
    float4 v = *(const float4*)&W1[(size_t)k * HID + n0];
    wt[(n0 + 0) * KP + k] = f2bf(v.x);
    wt[(n0 + 1) * KP + k] = f2bf(v.y);
    wt[(n0 + 2) * KP + k] = f2bf(v.z);
    wt[(n0 + 3) * KP + k] = f2bf(v.w);
  }
  __syncthreads();

  const int ar = rowBase + w * 16 + l15;
  const float* xrow = x + (size_t)((ar < N_NODES) ? ar : N_NODES - 1) * F_INDIM + quad * 8;

  floatx4 acc[4];
#pragma unroll
  for (int c = 0; c < 4; ++c) acc[c] = (floatx4){0.f, 0.f, 0.f, 0.f};

#pragma unroll
  for (int kc = 0; kc < F_INDIM; kc += 32) {
    const float4 va = *(const float4*)(xrow + kc);
    const float4 vb = *(const float4*)(xrow + kc + 4);
    short8 a;
    a[0] = (short)f2bf(va.x); a[1] = (short)f2bf(va.y);
    a[2] = (short)f2bf(va.z); a[3] = (short)f2bf(va.w);
    a[4] = (short)f2bf(vb.x); a[5] = (short)f2bf(vb.y);
    a[6] = (short)f2bf(vb.z); a[7] = (short)f2bf(vb.w);
#pragma unroll
    for (int c = 0; c < 4; ++c) {
      const short8 b = *(const short8*)&wt[(c * 16 + l15) * KP + kc + quad * 8];
      acc[c] = __builtin_amdgcn_mfma_f32_16x16x32_bf16(a, b, acc[c], 0, 0, 0);
    }
  }

#pragma unroll
  for (int reg = 0; reg < 4; ++reg) {
    int gr = rowBase + w * 16 + quad * 4 + reg;
    if (gr < N_NODES) {
      float d = dis[gr];
#pragma unroll
      for (int c = 0; c < 4; ++c)
        h1b[(size_t)gr * HID + c * 16 + l15] = f2bf(d * acc[c][reg]);
    }
  }
}

// ---------------- agg1: ab = bf16(relu(dis[n]*(self+sum) + b1)) ----------------
// one wave per node; 8 lanes per row (uint4 each) -> 8 edges per gather instr.
// lane = (g = lane>>3 edge group, q = lane&7 row quad); acc 8 feats/lane.

__global__ __launch_bounds__(256) void k_agg1(const int* __restrict__ esrc,
                                              const int* __restrict__ start,
                                              const float* __restrict__ dis,
                                              const unsigned short* __restrict__ h1b,
                                              const float* __restrict__ b1,
                                              unsigned short* __restrict__ ab) {
  int gid = blockIdx.x * 256 + threadIdx.x;
  int wid = gid >> 6;
  int lane = gid & 63;
  if (wid >= N_NODES) return;
  const int g = lane >> 3;
  const int q = lane & 7;
  const uint4* hp4 = (const uint4*)h1b;    // row = 8 quads of 16B
  int i = start[wid];
  const int e1 = start[wid + 1];
  float acc[8];
#pragma unroll
  for (int j = 0; j < 8; ++j) acc[j] = 0.f;
  for (; i + 16 <= e1; i += 16) {
    int sA = esrc[i + g];
    int sB = esrc[i + 8 + g];
    uint4 uA = hp4[(size_t)sA * 8 + q];
    uint4 uB = hp4[(size_t)sB * 8 + q];
    add8(acc, uA);
    add8(acc, uB);
  }
  if (i + 8 <= e1) {
    int s = esrc[i + g];
    uint4 u = hp4[(size_t)s * 8 + q];
    add8(acc, u);
    i += 8;
  }
  int rem = e1 - i;
  if (g < rem) {
    int s = esrc[i + g];
    uint4 u = hp4[(size_t)s * 8 + q];
    add8(acc, u);
  }
  // reduce across the 8 edge groups (lane bits 3..5)
#pragma unroll
  for (int off = 8; off < 64; off <<= 1) {
#pragma unroll
    for (int j = 0; j < 8; ++j) acc[j] += __shfl_xor(acc[j], off);
  }
  if (g == 0) {   // lanes 0..7 finalize+write; lane q owns feats q*8..q*8+7
    uint4 us = hp4[(size_t)wid * 8 + q];
    add8(acc, us);                          // self term (pre-scaled)
    float d = dis[wid];
    float4 ba = *(const float4*)&b1[q * 8];
    float4 bb = *(const float4*)&b1[q * 8 + 4];
    float v0 = fmaxf(d * acc[0] + ba.x, 0.f);
    float v1 = fmaxf(d * acc[1] + ba.y, 0.f);
    float v2 = fmaxf(d * acc[2] + ba.z, 0.f);
    float v3 = fmaxf(d * acc[3] + ba.w, 0.f);
    float v4 = fmaxf(d * acc[4] + bb.x, 0.f);
    float v5 = fmaxf(d * acc[5] + bb.y, 0.f);
    float v6 = fmaxf(d * acc[6] + bb.z, 0.f);
    float v7 = fmaxf(d * acc[7] + bb.w, 0.f);
    uint4 o;
    o.x = (unsigned)f2bf(v0) | ((unsigned)f2bf(v1) << 16);
    o.y = (unsigned)f2bf(v2) | ((unsigned)f2bf(v3) << 16);
    o.z = (unsigned)f2bf(v4) | ((unsigned)f2bf(v5) << 16);
    o.w = (unsigned)f2bf(v6) | ((unsigned)f2bf(v7) << 16);
    ((uint4*)ab)[(size_t)wid * 8 + q] = o;
  }
}

// ---------------- GEMM2 (MFMA): gb = bf16(dis[row] * (ab @ W2)), rows padded 64 ----

#define AP 72    // padded k-stride

__global__ __launch_bounds__(256) void k_gemm2(const unsigned short* __restrict__ ab,
                                               const float* __restrict__ W2,
                                               const float* __restrict__ dis,
                                               unsigned short* __restrict__ gb) {
  __shared__ unsigned short as[64 * AP];
  __shared__ unsigned short w2t[48 * AP];   // w2t[n][k] = bf16(W2[k][n]), 0-pad n>=40
  const int tid = threadIdx.x;
  const int lane = tid & 63;
  const int w = tid >> 6;
  const int quad = lane >> 4;
  const int l15 = lane & 15;
  const int rowBase = blockIdx.x * 64;

  for (int i = tid; i < 48 * 64; i += 256) {
    int n = i >> 6;
    int k = i & 63;
    w2t[n * AP + k] = (n < NCLS) ? f2bf(W2[(size_t)k * NCLS + n]) : (unsigned short)0;
  }
#pragma unroll
  for (int i = 0; i < 2; ++i) {
    int f = tid + 256 * i;
    int r = f >> 3;
    int q = f & 7;
    int gr = rowBase + r;
    short8 v = (short8){0, 0, 0, 0, 0, 0, 0, 0};
    if (gr < N_NODES) v = *(const short8*)&ab[(size_t)gr * HID + q * 8];
    *(short8*)&as[r * AP + q * 8] = v;
  }
  __syncthreads();

  floatx4 acc[3];
#pragma unroll
  for (int c = 0; c < 3; ++c) acc[c] = (floatx4){0.f, 0.f, 0.f, 0.f};

#pragma unroll
  for (int kh = 0; kh < 2; ++kh) {
    const short8 a = *(const short8*)&as[(w * 16 + l15) * AP + kh * 32 + quad * 8];
#pragma unroll
    for (int c = 0; c < 3; ++c) {
      const short8 b = *(const short8*)&w2t[(c * 16 + l15) * AP + kh * 32 + quad * 8];
      acc[c] = __builtin_amdgcn_mfma_f32_16x16x32_bf16(a, b, acc[c], 0, 0, 0);
    }
  }

#pragma unroll
  for (int reg = 0; reg < 4; ++reg) {
    int gr = rowBase + w * 16 + quad * 4 + reg;
    if (gr < N_NODES) {
      float d = dis[gr];
#pragma unroll
      for (int c = 0; c < 3; ++c) {
        int cc = c * 16 + l15;   // cols 0..47 (40..47 genuinely zero via padded W2)
        gb[(size_t)gr * 64 + cc] = f2bf(d * acc[c][reg]);
      }
      gb[(size_t)gr * 64 + 48 + l15] = 0;   // zero cols 48..63 for full-row gathers
    }
  }
}

// ---------------- agg2 + log_softmax fused: 8 lanes/row, 8 edges/instr --------

__global__ __launch_bounds__(256) void k_agg2ls(const int* __restrict__ esrc,
                                                const int* __restrict__ start,
                                                const float* __restrict__ dis,
                                                const unsigned short* __restrict__ gb,
                                                const float* __restrict__ b2,
                                                float* __restrict__ out) {
  int gid = blockIdx.x * 256 + threadIdx.x;
  int node = gid >> 6;
  int lane = gid & 63;
  if (node >= N_NODES) return;
  const int g = lane >> 3;
  const int q = lane & 7;
  const uint4* gp4 = (const uint4*)gb;
  int i = start[node];
  const int e1 = start[node + 1];
  float acc[8];
#pragma unroll
  for (int j = 0; j < 8; ++j) acc[j] = 0.f;
  for (; i + 16 <= e1; i += 16) {
    int sA = esrc[i + g];
    int sB = esrc[i + 8 + g];
    uint4 uA = gp4[(size_t)sA * 8 + q];
    uint4 uB = gp4[(size_t)sB * 8 + q];
    add8(acc, uA);
    add8(acc, uB);
  }
  if (i + 8 <= e1) {
    int s = esrc[i + g];
    uint4 u = gp4[(size_t)s * 8 + q];
    add8(acc, u);
    i += 8;
  }
  int rem = e1 - i;
  if (g < rem) {
    int s = esrc[i + g];
    uint4 u = gp4[(size_t)s * 8 + q];
    add8(acc, u);
  }
#pragma unroll
  for (int off = 8; off < 64; off <<= 1) {
#pragma unroll
    for (int j = 0; j < 8; ++j) acc[j] += __shfl_xor(acc[j], off);
  }
  // finalize on lanes 0..7; classes live in q<5 (cols 0..39), rest are zeros
  const bool wr = (g == 0) && (q < 5);
  float v0 = 0.f, v1 = 0.f, v2 = 0.f, v3 = 0.f, v4 = 0.f, v5 = 0.f, v6 = 0.f, v7 = 0.f;
  float m = -INFINITY;
  if (g == 0) {
    uint4 us = gp4[(size_t)node * 8 + q];
    add8(acc, us);                          // self (pre-scaled)
  }
  if (wr) {
    float d = dis[node];
    float4 ba = *(const float4*)&b2[q * 8];
    float4 bb = *(const float4*)&b2[q * 8 + 4];
    v0 = d * acc[0] + ba.x;
    v1 = d * acc[1] + ba.y;
    v2 = d * acc[2] + ba.z;
    v3 = d * acc[3] + ba.w;
    v4 = d * acc[4] + bb.x;
    v5 = d * acc[5] + bb.y;
    v6 = d * acc[6] + bb.z;
    v7 = d * acc[7] + bb.w;
    m = fmaxf(fmaxf(fmaxf(v0, v1), fmaxf(v2, v3)),
              fmaxf(fmaxf(v4, v5), fmaxf(v6, v7)));
  }
  // reduce max/sum across lanes 0..7 (offsets 1,2,4 suffice)
#pragma unroll
  for (int off = 1; off < 8; off <<= 1) m = fmaxf(m, __shfl_xor(m, off));
  float el = 0.f;
  if (wr) {
    el = __expf(v0 - m) + __expf(v1 - m) + __expf(v2 - m) + __expf(v3 - m) +
         __expf(v4 - m) + __expf(v5 - m) + __expf(v6 - m) + __expf(v7 - m);
  }
#pragma unroll
  for (int off = 1; off < 8; off <<= 1) el += __shfl_xor(el, off);
  float ls = logf(el);
  if (wr) {
    float4 o1 = make_float4(v0 - m - ls, v1 - m - ls, v2 - m - ls, v3 - m - ls);
    float4 o2 = make_float4(v4 - m - ls, v5 - m - ls, v6 - m - ls, v7 - m - ls);
    *(float4*)&out[(size_t)node * NCLS + q * 8] = o1;
    *(float4*)&out[(size_t)node * NCLS + q * 8 + 4] = o2;
  }
}

// ---------------- launch ----------------

extern "C" void kernel_launch(void* const* d_in, const int* in_sizes, int n_in,
                              void* d_out, int out_size, void* d_ws, size_t ws_size,
                              hipStream_t stream) {
  const float* x  = (const float*)d_in[0];
  const int*   ei = (const int*)d_in[1];
  const float* W1 = (const float*)d_in[2];
  const float* b1 = (const float*)d_in[3];
  const float* W2 = (const float*)d_in[4];
  const float* b2 = (const float*)d_in[5];
  float* out = (float*)d_out;

  const int* row = ei;             // edge_index[0] = src
  const int* col = ei + N_EDGES;   // edge_index[1] = dst

  // workspace layout (~41 MB)
  int*            esrc    = (int*)d_ws;                            // E ints     (6.4 MB)
  unsigned int*   bktdata = (unsigned int*)(esrc + N_EDGES);       // NBKT*CAP   (8.0 MB)
  unsigned short* h1b     = (unsigned short*)(bktdata + (size_t)NBKT * BKT_CAP); // 12.8 MB
  unsigned short* ab      = h1b + (size_t)N_NODES * HID;           // N*64 bf16  (12.8 MB)
  float*          dis     = (float*)(ab + (size_t)N_NODES * HID);  // N
  int*            degi    = (int*)(dis + N_NODES);                 // N
  int*            start   = degi + N_NODES;                        // N+1
  int*            gcur    = start + N_NODES + 1;                   // NBKT
  int*            bsum    = gcur + NBKT;                           // NB_SCAN
  int*            bsumS   = bsum + NB_SCAN;                        // NB_SCAN
  unsigned short* gb      = h1b;                                   // N*64 bf16, reuse

  k_zero<<<1, 256, 0, stream>>>(gcur, start);
  k_binA<<<(N_EDGES + EPB - 1) / EPB, 256, 0, stream>>>(row, col, gcur, bktdata);
  k_histdis<<<NBKT, 256, 0, stream>>>(gcur, bktdata, degi, dis);
  k_scan1<<<NB_SCAN, 256, 0, stream>>>(degi, start, bsum);
  k_scan2<<<1, 512, 0, stream>>>(bsum, bsumS);
  k_scan3<<<NB_SCAN, 256, 0, stream>>>(start, bsumS);
  k_place<<<NBKT, 256, 0, stream>>>(gcur, bktdata, start, esrc);

  k_gemm1<<<(N_NODES + 63) / 64, 256, 0, stream>>>(x, W1, dis, h1b);
  k_agg1<<<(N_NODES * 64 + 255) / 256, 256, 0, stream>>>(esrc, start, dis, h1b, b1, ab);

  k_gemm2<<<(N_NODES + 63) / 64, 256, 0, stream>>>(ab, W2, dis, gb);
  k_agg2ls<<<(N_NODES * 64 + 255) / 256, 256, 0, stream>>>(esrc, start, dis, gb, b2, out);
}

// Round 10
// 325.235 us; speedup vs baseline: 1.2587x; 1.0970x over previous
//
#include <hip/hip_runtime.h>
#include <math.h>

#define N_NODES 100000
#define N_EDGES 1600000
#define F_INDIM 256
#define HID 64
#define NCLS 40
#define NBKT 196         // ceil(N_NODES/512) coarse buckets of 512 dst nodes
#define BKT_CAP 10240    // per-bucket capacity (mean 8192 for uniform graph)
#define EPB 8192         // edges per block in k_binA

typedef __attribute__((ext_vector_type(8))) short short8;
typedef __attribute__((ext_vector_type(4))) float floatx4;

// ---- bf16 helpers (RNE) ----
__device__ __forceinline__ unsigned short f2bf(float f) {
  unsigned u = __float_as_uint(f);
  unsigned r = (u + 0x7FFFu + ((u >> 16) & 1u)) >> 16;
  return (unsigned short)r;
}
__device__ __forceinline__ float bf2f(unsigned short h) {
  return __uint_as_float(((unsigned)h) << 16);
}
// accumulate 8 packed bf16 (one 16B quad of a row) into 8 fp32 accumulators
__device__ __forceinline__ void add8(float* a, uint4 u) {
  a[0] += __uint_as_float(u.x << 16);
  a[1] += __uint_as_float(u.x & 0xFFFF0000u);
  a[2] += __uint_as_float(u.y << 16);
  a[3] += __uint_as_float(u.y & 0xFFFF0000u);
  a[4] += __uint_as_float(u.z << 16);
  a[5] += __uint_as_float(u.z & 0xFFFF0000u);
  a[6] += __uint_as_float(u.w << 16);
  a[7] += __uint_as_float(u.w & 0xFFFF0000u);
}

// ---------------- tiny init ----------------

__global__ __launch_bounds__(256) void k_zero(int* __restrict__ gcur,
                                              int* __restrict__ start) {
  int t = threadIdx.x;
  if (t < NBKT) gcur[t] = 0;
  if (t == 0) start[N_NODES] = N_EDGES;
}

// ---------------- phase A: coarse-bucket edges, clustered writes ----------------

__global__ __launch_bounds__(256) void k_binA(const int* __restrict__ row,
                                              const int* __restrict__ col,
                                              int* __restrict__ gcur,
                                              unsigned int* __restrict__ bktdata) {
  __shared__ int hist[NBKT];
  __shared__ int cur[NBKT];
  __shared__ int gbase[NBKT];
  const int t = threadIdx.x;
  const int e0 = blockIdx.x * EPB;
  const int n = min(EPB, N_EDGES - e0);
  if (t < NBKT) hist[t] = 0;
  __syncthreads();
  for (int i = t; i < n; i += 256) atomicAdd(&hist[col[e0 + i] >> 9], 1);
  __syncthreads();
  if (t < NBKT) {
    cur[t] = 0;
    int h = hist[t];
    gbase[t] = (h > 0) ? atomicAdd(&gcur[t], h) : 0;
  }
  __syncthreads();
  for (int i = t; i < n; i += 256) {
    int c = col[e0 + i];
    int r = row[e0 + i];
    int b = c >> 9;
    int p = atomicAdd(&cur[b], 1);
    bktdata[(size_t)b * BKT_CAP + gbase[b] + p] =
        ((unsigned)(c & 511) << 17) | (unsigned)r;
  }
}

// ---------------- phase B1: per-bucket hist -> dis + LOCAL exclusive scan -------
// lscan[i] = exclusive prefix of in-bucket degrees (bucket total == gcur[b]).

__global__ __launch_bounds__(256) void k_histdis(const int* __restrict__ gcur,
                                                 const unsigned int* __restrict__ bktdata,
                                                 int* __restrict__ lscan,
                                                 float* __restrict__ dis) {
  __shared__ int h[512];
  const int b = blockIdx.x, t = threadIdx.x;
  h[t] = 0; h[t + 256] = 0;
  __syncthreads();
  const int cnt = gcur[b];
  const unsigned int* p = bktdata + (size_t)b * BKT_CAP;
  for (int i = t; i < cnt; i += 256) atomicAdd(&h[p[i] >> 17], 1);
  __syncthreads();
  const int n0 = b * 512 + t, n1 = n0 + 256;
  const int c0 = h[t], c1 = h[t + 256];
  if (n0 < N_NODES) dis[n0] = rsqrtf((float)(c0 + 1));
  if (n1 < N_NODES) dis[n1] = rsqrtf((float)(c1 + 1));
  // inclusive Hillis-Steele over 512 entries (2 per thread)
#pragma unroll
  for (int off = 1; off < 512; off <<= 1) {
    int u0 = (t >= off) ? h[t - off] : 0;
    int u1 = ((t + 256) >= off) ? h[t + 256 - off] : 0;
    __syncthreads();
    h[t] += u0; h[t + 256] += u1;
    __syncthreads();
  }
  if (n0 < N_NODES) lscan[n0] = h[t] - c0;          // exclusive
  if (n1 < N_NODES) lscan[n1] = h[t + 256] - c1;
}

// ---------------- scan over bucket totals (gcur) -> bsumS ----------------

__global__ __launch_bounds__(256) void k_scan2(const int* __restrict__ gcur,
                                               int* __restrict__ bsumS) {
  __shared__ int s[256];
  const int t = threadIdx.x;
  int v = (t < NBKT) ? gcur[t] : 0;
  s[t] = v;
  __syncthreads();
#pragma unroll
  for (int off = 1; off < 256; off <<= 1) {
    int u = (t >= off) ? s[t - off] : 0;
    __syncthreads();
    s[t] += u;
    __syncthreads();
  }
  if (t < NBKT) bsumS[t] = s[t] - v;
}

// ---------------- phase B2: placement + start materialization ----------------

__global__ __launch_bounds__(256) void k_place(const int* __restrict__ gcur,
                                               const unsigned int* __restrict__ bktdata,
                                               const int* __restrict__ lscan,
                                               const int* __restrict__ bsumS,
                                               int* __restrict__ start,
                                               int* __restrict__ esrc) {
  __shared__ int cur[512];
  __shared__ int sbase[512];
  const int b = blockIdx.x, t = threadIdx.x;
  const int base = bsumS[b];
  const int n0 = b * 512 + t, n1 = n0 + 256;
  int s0 = ((n0 < N_NODES) ? lscan[n0] : 0) + base;
  int s1 = ((n1 < N_NODES) ? lscan[n1] : 0) + base;
  sbase[t] = s0; sbase[t + 256] = s1;
  if (n0 < N_NODES) start[n0] = s0;
  if (n1 < N_NODES) start[n1] = s1;
  cur[t] = 0; cur[t + 256] = 0;
  __syncthreads();
  const int cnt = gcur[b];
  const unsigned int* p = bktdata + (size_t)b * BKT_CAP;
  for (int i = t; i < cnt; i += 256) {
    unsigned u = p[i];
    int ld = u >> 17;
    int src = u & 0x1FFFF;
    int pos = sbase[ld] + atomicAdd(&cur[ld], 1);
    esrc[pos] = src;
  }
}

// ---------------- GEMM1 (MFMA): h1b = bf16(dis[row] * (x @ W1)) ----------------
// A-fragments direct from global (x has zero cross-block reuse); W1^T in LDS.

#define KP 264   // padded k-stride for wt (2-way bank aliasing only = free)

__global__ __launch_bounds__(256) void k_gemm1(const float* __restrict__ x,
                                               const float* __restrict__ W1,
                                               const float* __restrict__ dis,
                                               unsigned short* __restrict__ h1b) {
  __shared__ unsigned short wt[HID * KP];   // wt[n][k] = bf16(W1[k][n])
  const int tid = threadIdx.x;
  const int lane = tid & 63;
  const int w = tid >> 6;
  const int quad = lane >> 4;
  const int l15 = lane & 15;
  const int rowBase = blockIdx.x * 64;

#pragma unroll
  for (int i = 0; i < 16; ++i) {
    int f = tid + 256 * i;
    int k = f >> 4;
    int n0 = (f & 15) * 4;
    float4 v = *(const float4*)&W1[(size_t)k * HID + n0];
    wt[(n0 + 0) * KP + k] = f2bf(v.x);
    wt[(n0 + 1) * KP + k] = f2bf(v.y);
    wt[(n0 + 2) * KP + k] = f2bf(v.z);
    wt[(n0 + 3) * KP + k] = f2bf(v.w);
  }
  __syncthreads();

  const int ar = rowBase + w * 16 + l15;
  const float* xrow = x + (size_t)((ar < N_NODES) ? ar : N_NODES - 1) * F_INDIM + quad * 8;

  floatx4 acc[4];
#pragma unroll
  for (int c = 0; c < 4; ++c) acc[c] = (floatx4){0.f, 0.f, 0.f, 0.f};

#pragma unroll
  for (int kc = 0; kc < F_INDIM; kc += 32) {
    const float4 va = *(const float4*)(xrow + kc);
    const float4 vb = *(const float4*)(xrow + kc + 4);
    short8 a;
    a[0] = (short)f2bf(va.x); a[1] = (short)f2bf(va.y);
    a[2] = (short)f2bf(va.z); a[3] = (short)f2bf(va.w);
    a[4] = (short)f2bf(vb.x); a[5] = (short)f2bf(vb.y);
    a[6] = (short)f2bf(vb.z); a[7] = (short)f2bf(vb.w);
#pragma unroll
    for (int c = 0; c < 4; ++c) {
      const short8 b = *(const short8*)&wt[(c * 16 + l15) * KP + kc + quad * 8];
      acc[c] = __builtin_amdgcn_mfma_f32_16x16x32_bf16(a, b, acc[c], 0, 0, 0);
    }
  }

#pragma unroll
  for (int reg = 0; reg < 4; ++reg) {
    int gr = rowBase + w * 16 + quad * 4 + reg;
    if (gr < N_NODES) {
      float d = dis[gr];
#pragma unroll
      for (int c = 0; c < 4; ++c)
        h1b[(size_t)gr * HID + c * 16 + l15] = f2bf(d * acc[c][reg]);
    }
  }
}

// ---------------- agg1: ab = bf16(relu(dis[n]*(self+sum) + b1)) ----------------
// one node per 8-lane group (8 nodes/wave), 2 edges in flight per group; a
// gather instruction serves 8 rows x 16B; no cross-group reduction needed.

__global__ __launch_bounds__(256) void k_agg1(const int* __restrict__ esrc,
                                              const int* __restrict__ start,
                                              const float* __restrict__ dis,
                                              const unsigned short* __restrict__ h1b,
                                              const float* __restrict__ b1,
                                              unsigned short* __restrict__ ab) {
  int gid = blockIdx.x * 256 + threadIdx.x;
  int node = gid >> 3;
  int q = gid & 7;
  if (node >= N_NODES) return;
  const uint4* hp4 = (const uint4*)h1b;    // row = 8 quads of 16B
  int i = start[node];
  const int e1 = start[node + 1];
  float acc[8];
#pragma unroll
  for (int j = 0; j < 8; ++j) acc[j] = 0.f;
  for (; i + 2 <= e1; i += 2) {
    int s0 = esrc[i];
    int s1 = esrc[i + 1];
    uint4 u0 = hp4[(size_t)s0 * 8 + q];
    uint4 u1 = hp4[(size_t)s1 * 8 + q];
    add8(acc, u0);
    add8(acc, u1);
  }
  if (i < e1) {
    uint4 u = hp4[(size_t)esrc[i] * 8 + q];
    add8(acc, u);
  }
  uint4 us = hp4[(size_t)node * 8 + q];
  add8(acc, us);                           // self term (pre-scaled)
  float d = dis[node];
  float4 ba = *(const float4*)&b1[q * 8];
  float4 bb = *(const float4*)&b1[q * 8 + 4];
  float v0 = fmaxf(d * acc[0] + ba.x, 0.f);
  float v1 = fmaxf(d * acc[1] + ba.y, 0.f);
  float v2 = fmaxf(d * acc[2] + ba.z, 0.f);
  float v3 = fmaxf(d * acc[3] + ba.w, 0.f);
  float v4 = fmaxf(d * acc[4] + bb.x, 0.f);
  float v5 = fmaxf(d * acc[5] + bb.y, 0.f);
  float v6 = fmaxf(d * acc[6] + bb.z, 0.f);
  float v7 = fmaxf(d * acc[7] + bb.w, 0.f);
  uint4 o;
  o.x = (unsigned)f2bf(v0) | ((unsigned)f2bf(v1) << 16);
  o.y = (unsigned)f2bf(v2) | ((unsigned)f2bf(v3) << 16);
  o.z = (unsigned)f2bf(v4) | ((unsigned)f2bf(v5) << 16);
  o.w = (unsigned)f2bf(v6) | ((unsigned)f2bf(v7) << 16);
  ((uint4*)ab)[(size_t)node * 8 + q] = o;
}

// ---------------- GEMM2 (MFMA): gb = bf16(dis[row] * (ab @ W2)), rows padded 64 ----

#define AP 72    // padded k-stride

__global__ __launch_bounds__(256) void k_gemm2(const unsigned short* __restrict__ ab,
                                               const float* __restrict__ W2,
                                               const float* __restrict__ dis,
                                               unsigned short* __restrict__ gb) {
  __shared__ unsigned short as[64 * AP];
  __shared__ unsigned short w2t[48 * AP];   // w2t[n][k] = bf16(W2[k][n]), 0-pad n>=40
  const int tid = threadIdx.x;
  const int lane = tid & 63;
  const int w = tid >> 6;
  const int quad = lane >> 4;
  const int l15 = lane & 15;
  const int rowBase = blockIdx.x * 64;

  for (int i = tid; i < 48 * 64; i += 256) {
    int n = i >> 6;
    int k = i & 63;
    w2t[n * AP + k] = (n < NCLS) ? f2bf(W2[(size_t)k * NCLS + n]) : (unsigned short)0;
  }
#pragma unroll
  for (int i = 0; i < 2; ++i) {
    int f = tid + 256 * i;
    int r = f >> 3;
    int q = f & 7;
    int gr = rowBase + r;
    short8 v = (short8){0, 0, 0, 0, 0, 0, 0, 0};
    if (gr < N_NODES) v = *(const short8*)&ab[(size_t)gr * HID + q * 8];
    *(short8*)&as[r * AP + q * 8] = v;
  }
  __syncthreads();

  floatx4 acc[3];
#pragma unroll
  for (int c = 0; c < 3; ++c) acc[c] = (floatx4){0.f, 0.f, 0.f, 0.f};

#pragma unroll
  for (int kh = 0; kh < 2; ++kh) {
    const short8 a = *(const short8*)&as[(w * 16 + l15) * AP + kh * 32 + quad * 8];
#pragma unroll
    for (int c = 0; c < 3; ++c) {
      const short8 b = *(const short8*)&w2t[(c * 16 + l15) * AP + kh * 32 + quad * 8];
      acc[c] = __builtin_amdgcn_mfma_f32_16x16x32_bf16(a, b, acc[c], 0, 0, 0);
    }
  }

#pragma unroll
  for (int reg = 0; reg < 4; ++reg) {
    int gr = rowBase + w * 16 + quad * 4 + reg;
    if (gr < N_NODES) {
      float d = dis[gr];
#pragma unroll
      for (int c = 0; c < 3; ++c) {
        int cc = c * 16 + l15;   // cols 0..47 (40..47 genuinely zero via padded W2)
        gb[(size_t)gr * 64 + cc] = f2bf(d * acc[c][reg]);
      }
      gb[(size_t)gr * 64 + 48 + l15] = 0;   // zero cols 48..63 for full-row gathers
    }
  }
}

// ---------------- agg2 + log_softmax fused: one node per 8-lane group ----------

__global__ __launch_bounds__(256) void k_agg2ls(const int* __restrict__ esrc,
                                                const int* __restrict__ start,
                                                const float* __restrict__ dis,
                                                const unsigned short* __restrict__ gb,
                                                const float* __restrict__ b2,
                                                float* __restrict__ out) {
  int gid = blockIdx.x * 256 + threadIdx.x;
  int node = gid >> 3;
  int q = gid & 7;
  if (node >= N_NODES) return;
  const uint4* gp4 = (const uint4*)gb;
  int i = start[node];
  const int e1 = start[node + 1];
  float acc[8];
#pragma unroll
  for (int j = 0; j < 8; ++j) acc[j] = 0.f;
  for (; i + 2 <= e1; i += 2) {
    int s0 = esrc[i];
    int s1 = esrc[i + 1];
    uint4 u0 = gp4[(size_t)s0 * 8 + q];
    uint4 u1 = gp4[(size_t)s1 * 8 + q];
    add8(acc, u0);
    add8(acc, u1);
  }
  if (i < e1) {
    uint4 u = gp4[(size_t)esrc[i] * 8 + q];
    add8(acc, u);
  }
  uint4 us = gp4[(size_t)node * 8 + q];
  add8(acc, us);                           // self (pre-scaled)
  // classes live in quads q<5 (cols 0..39); q>=5 quads are zeros by construction
  const bool wr = q < 5;
  float v0 = 0.f, v1 = 0.f, v2 = 0.f, v3 = 0.f, v4 = 0.f, v5 = 0.f, v6 = 0.f, v7 = 0.f;
  float m = -INFINITY;
  if (wr) {
    float d = dis[node];
    float4 ba = *(const float4*)&b2[q * 8];
    float4 bb = *(const float4*)&b2[q * 8 + 4];
    v0 = d * acc[0] + ba.x;
    v1 = d * acc[1] + ba.y;
    v2 = d * acc[2] + ba.z;
    v3 = d * acc[3] + ba.w;
    v4 = d * acc[4] + bb.x;
    v5 = d * acc[5] + bb.y;
    v6 = d * acc[6] + bb.z;
    v7 = d * acc[7] + bb.w;
    m = fmaxf(fmaxf(fmaxf(v0, v1), fmaxf(v2, v3)),
              fmaxf(fmaxf(v4, v5), fmaxf(v6, v7)));
  }
  // reduce max/sum within the 8-lane group (offsets 1,2,4 stay inside group)
#pragma unroll
  for (int off = 1; off < 8; off <<= 1) m = fmaxf(m, __shfl_xor(m, off));
  float el = 0.f;
  if (wr) {
    el = __expf(v0 - m) + __expf(v1 - m) + __expf(v2 - m) + __expf(v3 - m) +
         __expf(v4 - m) + __expf(v5 - m) + __expf(v6 - m) + __expf(v7 - m);
  }
#pragma unroll
  for (int off = 1; off < 8; off <<= 1) el += __shfl_xor(el, off);
  float ls = logf(el);
  if (wr) {
    float4 o1 = make_float4(v0 - m - ls, v1 - m - ls, v2 - m - ls, v3 - m - ls);
    float4 o2 = make_float4(v4 - m - ls, v5 - m - ls, v6 - m - ls, v7 - m - ls);
    *(float4*)&out[(size_t)node * NCLS + q * 8] = o1;
    *(float4*)&out[(size_t)node * NCLS + q * 8 + 4] = o2;
  }
}

// ---------------- launch ----------------

extern "C" void kernel_launch(void* const* d_in, const int* in_sizes, int n_in,
                              void* d_out, int out_size, void* d_ws, size_t ws_size,
                              hipStream_t stream) {
  const float* x  = (const float*)d_in[0];
  const int*   ei = (const int*)d_in[1];
  const float* W1 = (const float*)d_in[2];
  const float* b1 = (const float*)d_in[3];
  const float* W2 = (const float*)d_in[4];
  const float* b2 = (const float*)d_in[5];
  float* out = (float*)d_out;

  const int* row = ei;             // edge_index[0] = src
  const int* col = ei + N_EDGES;   // edge_index[1] = dst

  // workspace layout (~41 MB)
  int*            esrc    = (int*)d_ws;                            // E ints     (6.4 MB)
  unsigned int*   bktdata = (unsigned int*)(esrc + N_EDGES);       // NBKT*CAP   (8.0 MB)
  unsigned short* h1b     = (unsigned short*)(bktdata + (size_t)NBKT * BKT_CAP); // 12.8 MB
  unsigned short* ab      = h1b + (size_t)N_NODES * HID;           // N*64 bf16  (12.8 MB)
  float*          dis     = (float*)(ab + (size_t)N_NODES * HID);  // N
  int*            lscan   = (int*)(dis + N_NODES);                 // N
  int*            start   = lscan + N_NODES;                       // N+1
  int*            gcur    = start + N_NODES + 1;                   // NBKT
  int*            bsumS   = gcur + NBKT;                           // NBKT
  unsigned short* gb      = h1b;                                   // N*64 bf16, reuse

  k_zero<<<1, 256, 0, stream>>>(gcur, start);
  k_binA<<<(N_EDGES + EPB - 1) / EPB, 256, 0, stream>>>(row, col, gcur, bktdata);
  k_histdis<<<NBKT, 256, 0, stream>>>(gcur, bktdata, lscan, dis);
  k_scan2<<<1, 256, 0, stream>>>(gcur, bsumS);
  k_place<<<NBKT, 256, 0, stream>>>(gcur, bktdata, lscan, bsumS, start, esrc);

  k_gemm1<<<(N_NODES + 63) / 64, 256, 0, stream>>>(x, W1, dis, h1b);
  k_agg1<<<(N_NODES * 8 + 255) / 256, 256, 0, stream>>>(esrc, start, dis, h1b, b1, ab);

  k_gemm2<<<(N_NODES + 63) / 64, 256, 0, stream>>>(ab, W2, dis, gb);
  k_agg2ls<<<(N_NODES * 8 + 255) / 256, 256, 0, stream>>>(esrc, start, dis, gb, b2, out);
}

// Round 11
// 316.290 us; speedup vs baseline: 1.2943x; 1.0283x over previous
//
#include <hip/hip_runtime.h>
#include <math.h>

#define N_NODES 100000
#define N_EDGES 1600000
#define F_INDIM 256
#define HID 64
#define NCLS 40
#define NBKT 196         // ceil(N_NODES/512) coarse buckets of 512 dst nodes
#define BKT_CAP 10240    // per-bucket capacity (mean 8192 for uniform graph)
#define EPB 8192         // edges per block in k_binA

typedef __attribute__((ext_vector_type(8))) short short8;
typedef __attribute__((ext_vector_type(4))) float floatx4;

// ---- bf16 helpers (RNE) ----
__device__ __forceinline__ unsigned short f2bf(float f) {
  unsigned u = __float_as_uint(f);
  unsigned r = (u + 0x7FFFu + ((u >> 16) & 1u)) >> 16;
  return (unsigned short)r;
}
__device__ __forceinline__ float bf2f(unsigned short h) {
  return __uint_as_float(((unsigned)h) << 16);
}
// accumulate 8 packed bf16 (one 16B quad of a row) into 8 fp32 accumulators
__device__ __forceinline__ void add8(float* a, uint4 u) {
  a[0] += __uint_as_float(u.x << 16);
  a[1] += __uint_as_float(u.x & 0xFFFF0000u);
  a[2] += __uint_as_float(u.y << 16);
  a[3] += __uint_as_float(u.y & 0xFFFF0000u);
  a[4] += __uint_as_float(u.z << 16);
  a[5] += __uint_as_float(u.z & 0xFFFF0000u);
  a[6] += __uint_as_float(u.w << 16);
  a[7] += __uint_as_float(u.w & 0xFFFF0000u);
}

// ---------------- tiny init: zero bucket cursors ----------------

__global__ __launch_bounds__(256) void k_zero(int* __restrict__ gcur) {
  int t = threadIdx.x;
  if (t < NBKT) gcur[t] = 0;
}

// ---------------- phase A: coarse-bucket edges, clustered writes ----------------

__global__ __launch_bounds__(256) void k_binA(const int* __restrict__ row,
                                              const int* __restrict__ col,
                                              int* __restrict__ gcur,
                                              unsigned int* __restrict__ bktdata) {
  __shared__ int hist[NBKT];
  __shared__ int cur[NBKT];
  __shared__ int gbase[NBKT];
  const int t = threadIdx.x;
  const int e0 = blockIdx.x * EPB;
  const int n = min(EPB, N_EDGES - e0);
  if (t < NBKT) hist[t] = 0;
  __syncthreads();
  for (int i = t; i < n; i += 256) atomicAdd(&hist[col[e0 + i] >> 9], 1);
  __syncthreads();
  if (t < NBKT) {
    cur[t] = 0;
    int h = hist[t];
    gbase[t] = (h > 0) ? atomicAdd(&gcur[t], h) : 0;
  }
  __syncthreads();
  for (int i = t; i < n; i += 256) {
    int c = col[e0 + i];
    int r = row[e0 + i];
    int b = c >> 9;
    int p = atomicAdd(&cur[b], 1);
    bktdata[(size_t)b * BKT_CAP + gbase[b] + p] =
        ((unsigned)(c & 511) << 17) | (unsigned)r;
  }
}

// ---------------- phase B (fused): hist + dis + local scan + base + placement ----
// One block per bucket. All data deps are intra-bucket; global base for the
// bucket is a cheap in-block reduction over gcur[0..b-1] (replaces scan2).

__global__ __launch_bounds__(256) void k_build2(const int* __restrict__ gcur,
                                                const unsigned int* __restrict__ bktdata,
                                                float* __restrict__ dis,
                                                int* __restrict__ start,
                                                int* __restrict__ esrc) {
  __shared__ int h[512];
  __shared__ int cur[512];
  __shared__ int sbase[512];
  __shared__ int wsum[4];
  const int b = blockIdx.x, t = threadIdx.x;
  h[t] = 0; h[t + 256] = 0; cur[t] = 0; cur[t + 256] = 0;
  // base = sum gcur[0..b-1]  (NBKT=196 < 256: one element per thread)
  int pv = (t < b) ? gcur[t] : 0;
#pragma unroll
  for (int off = 1; off < 64; off <<= 1) pv += __shfl_xor(pv, off);
  if ((t & 63) == 0) wsum[t >> 6] = pv;
  if (b == 0 && t == 0) start[N_NODES] = N_EDGES;   // sentinel
  __syncthreads();
  const int base = wsum[0] + wsum[1] + wsum[2] + wsum[3];

  const int cnt = gcur[b];
  const unsigned int* p = bktdata + (size_t)b * BKT_CAP;
  for (int i = t; i < cnt; i += 256) atomicAdd(&h[p[i] >> 17], 1);
  __syncthreads();

  const int n0 = b * 512 + t, n1 = n0 + 256;
  const int c0 = h[t], c1 = h[t + 256];
  if (n0 < N_NODES) dis[n0] = rsqrtf((float)(c0 + 1));
  if (n1 < N_NODES) dis[n1] = rsqrtf((float)(c1 + 1));
  // inclusive Hillis-Steele over 512 entries (2 per thread)
#pragma unroll
  for (int off = 1; off < 512; off <<= 1) {
    int u0 = (t >= off) ? h[t - off] : 0;
    int u1 = ((t + 256) >= off) ? h[t + 256 - off] : 0;
    __syncthreads();
    h[t] += u0; h[t + 256] += u1;
    __syncthreads();
  }
  const int sb0 = base + h[t] - c0;          // exclusive + global base
  const int sb1 = base + h[t + 256] - c1;
  sbase[t] = sb0; sbase[t + 256] = sb1;
  if (n0 < N_NODES) start[n0] = sb0;
  if (n1 < N_NODES) start[n1] = sb1;
  __syncthreads();

  for (int i = t; i < cnt; i += 256) {
    unsigned u = p[i];
    int ld = u >> 17;
    int src = u & 0x1FFFF;
    int pos = sbase[ld] + atomicAdd(&cur[ld], 1);
    esrc[pos] = src;
  }
}

// ---------------- GEMM1 (MFMA): h1b = bf16(dis[row] * (x @ W1)) ----------------
// A-fragments direct from global (x has zero cross-block reuse); W1^T in LDS.

#define KP 264   // padded k-stride for wt (2-way bank aliasing only = free)

__global__ __launch_bounds__(256) void k_gemm1(const float* __restrict__ x,
                                               const float* __restrict__ W1,
                                               const float* __restrict__ dis,
                                               unsigned short* __restrict__ h1b) {
  __shared__ unsigned short wt[HID * KP];   // wt[n][k] = bf16(W1[k][n])
  const int tid = threadIdx.x;
  const int lane = tid & 63;
  const int w = tid >> 6;
  const int quad = lane >> 4;
  const int l15 = lane & 15;
  const int rowBase = blockIdx.x * 64;

#pragma unroll
  for (int i = 0; i < 16; ++i) {
    int f = tid + 256 * i;
    int k = f >> 4;
    int n0 = (f & 15) * 4;
    float4 v = *(const float4*)&W1[(size_t)k * HID + n0];
    wt[(n0 + 0) * KP + k] = f2bf(v.x);
    wt[(n0 + 1) * KP + k] = f2bf(v.y);
    wt[(n0 + 2) * KP + k] = f2bf(v.z);
    wt[(n0 + 3) * KP + k] = f2bf(v.w);
  }
  __syncthreads();

  const int ar = rowBase + w * 16 + l15;
  const float* xrow = x + (size_t)((ar < N_NODES) ? ar : N_NODES - 1) * F_INDIM + quad * 8;

  floatx4 acc[4];
#pragma unroll
  for (int c = 0; c < 4; ++c) acc[c] = (floatx4){0.f, 0.f, 0.f, 0.f};

#pragma unroll
  for (int kc = 0; kc < F_INDIM; kc += 32) {
    const float4 va = *(const float4*)(xrow + kc);
    const float4 vb = *(const float4*)(xrow + kc + 4);
    short8 a;
    a[0] = (short)f2bf(va.x); a[1] = (short)f2bf(va.y);
    a[2] = (short)f2bf(va.z); a[3] = (short)f2bf(va.w);
    a[4] = (short)f2bf(vb.x); a[5] = (short)f2bf(vb.y);
    a[6] = (short)f2bf(vb.z); a[7] = (short)f2bf(vb.w);
#pragma unroll
    for (int c = 0; c < 4; ++c) {
      const short8 b = *(const short8*)&wt[(c * 16 + l15) * KP + kc + quad * 8];
      acc[c] = __builtin_amdgcn_mfma_f32_16x16x32_bf16(a, b, acc[c], 0, 0, 0);
    }
  }

#pragma unroll
  for (int reg = 0; reg < 4; ++reg) {
    int gr = rowBase + w * 16 + quad * 4 + reg;
    if (gr < N_NODES) {
      float d = dis[gr];
#pragma unroll
      for (int c = 0; c < 4; ++c)
        h1b[(size_t)gr * HID + c * 16 + l15] = f2bf(d * acc[c][reg]);
    }
  }
}

// ---------------- agg1: ab = bf16(relu(dis[n]*(self+sum) + b1)) ----------------
// one node per 8-lane group (8 nodes/wave); 4 edges in flight per group.

__global__ __launch_bounds__(256) void k_agg1(const int* __restrict__ esrc,
                                              const int* __restrict__ start,
                                              const float* __restrict__ dis,
                                              const unsigned short* __restrict__ h1b,
                                              const float* __restrict__ b1,
                                              unsigned short* __restrict__ ab) {
  int gid = blockIdx.x * 256 + threadIdx.x;
  int node = gid >> 3;
  int q = gid & 7;
  if (node >= N_NODES) return;
  const uint4* hp4 = (const uint4*)h1b;    // row = 8 quads of 16B
  int i = start[node];
  const int e1 = start[node + 1];
  float acc[8];
#pragma unroll
  for (int j = 0; j < 8; ++j) acc[j] = 0.f;
  for (; i + 4 <= e1; i += 4) {
    int s0 = esrc[i];
    int s1 = esrc[i + 1];
    int s2 = esrc[i + 2];
    int s3 = esrc[i + 3];
    uint4 u0 = hp4[(size_t)s0 * 8 + q];
    uint4 u1 = hp4[(size_t)s1 * 8 + q];
    uint4 u2 = hp4[(size_t)s2 * 8 + q];
    uint4 u3 = hp4[(size_t)s3 * 8 + q];
    add8(acc, u0);
    add8(acc, u1);
    add8(acc, u2);
    add8(acc, u3);
  }
  for (; i < e1; ++i) {
    uint4 u = hp4[(size_t)esrc[i] * 8 + q];
    add8(acc, u);
  }
  uint4 us = hp4[(size_t)node * 8 + q];
  add8(acc, us);                           // self term (pre-scaled)
  float d = dis[node];
  float4 ba = *(const float4*)&b1[q * 8];
  float4 bb = *(const float4*)&b1[q * 8 + 4];
  float v0 = fmaxf(d * acc[0] + ba.x, 0.f);
  float v1 = fmaxf(d * acc[1] + ba.y, 0.f);
  float v2 = fmaxf(d * acc[2] + ba.z, 0.f);
  float v3 = fmaxf(d * acc[3] + ba.w, 0.f);
  float v4 = fmaxf(d * acc[4] + bb.x, 0.f);
  float v5 = fmaxf(d * acc[5] + bb.y, 0.f);
  float v6 = fmaxf(d * acc[6] + bb.z, 0.f);
  float v7 = fmaxf(d * acc[7] + bb.w, 0.f);
  uint4 o;
  o.x = (unsigned)f2bf(v0) | ((unsigned)f2bf(v1) << 16);
  o.y = (unsigned)f2bf(v2) | ((unsigned)f2bf(v3) << 16);
  o.z = (unsigned)f2bf(v4) | ((unsigned)f2bf(v5) << 16);
  o.w = (unsigned)f2bf(v6) | ((unsigned)f2bf(v7) << 16);
  ((uint4*)ab)[(size_t)node * 8 + q] = o;
}

// ---------------- GEMM2 (MFMA): gb = bf16(dis[row] * (ab @ W2)), rows padded 64 ----

#define AP 72    // padded k-stride

__global__ __launch_bounds__(256) void k_gemm2(const unsigned short* __restrict__ ab,
                                               const float* __restrict__ W2,
                                               const float* __restrict__ dis,
                                               unsigned short* __restrict__ gb) {
  __shared__ unsigned short as[64 * AP];
  __shared__ unsigned short w2t[48 * AP];   // w2t[n][k] = bf16(W2[k][n]), 0-pad n>=40
  const int tid = threadIdx.x;
  const int lane = tid & 63;
  const int w = tid >> 6;
  const int quad = lane >> 4;
  const int l15 = lane & 15;
  const int rowBase = blockIdx.x * 64;

  for (int i = tid; i < 48 * 64; i += 256) {
    int n = i >> 6;
    int k = i & 63;
    w2t[n * AP + k] = (n < NCLS) ? f2bf(W2[(size_t)k * NCLS + n]) : (unsigned short)0;
  }
#pragma unroll
  for (int i = 0; i < 2; ++i) {
    int f = tid + 256 * i;
    int r = f >> 3;
    int q = f & 7;
    int gr = rowBase + r;
    short8 v = (short8){0, 0, 0, 0, 0, 0, 0, 0};
    if (gr < N_NODES) v = *(const short8*)&ab[(size_t)gr * HID + q * 8];
    *(short8*)&as[r * AP + q * 8] = v;
  }
  __syncthreads();

  floatx4 acc[3];
#pragma unroll
  for (int c = 0; c < 3; ++c) acc[c] = (floatx4){0.f, 0.f, 0.f, 0.f};

#pragma unroll
  for (int kh = 0; kh < 2; ++kh) {
    const short8 a = *(const short8*)&as[(w * 16 + l15) * AP + kh * 32 + quad * 8];
#pragma unroll
    for (int c = 0; c < 3; ++c) {
      const short8 b = *(const short8*)&w2t[(c * 16 + l15) * AP + kh * 32 + quad * 8];
      acc[c] = __builtin_amdgcn_mfma_f32_16x16x32_bf16(a, b, acc[c], 0, 0, 0);
    }
  }

#pragma unroll
  for (int reg = 0; reg < 4; ++reg) {
    int gr = rowBase + w * 16 + quad * 4 + reg;
    if (gr < N_NODES) {
      float d = dis[gr];
#pragma unroll
      for (int c = 0; c < 3; ++c) {
        int cc = c * 16 + l15;   // cols 0..47 (40..47 genuinely zero via padded W2)
        gb[(size_t)gr * 64 + cc] = f2bf(d * acc[c][reg]);
      }
      gb[(size_t)gr * 64 + 48 + l15] = 0;   // zero cols 48..63 for full-row gathers
    }
  }
}

// ---------------- agg2 + log_softmax fused: one node per 8-lane group ----------

__global__ __launch_bounds__(256) void k_agg2ls(const int* __restrict__ esrc,
                                                const int* __restrict__ start,
                                                const float* __restrict__ dis,
                                                const unsigned short* __restrict__ gb,
                                                const float* __restrict__ b2,
                                                float* __restrict__ out) {
  int gid = blockIdx.x * 256 + threadIdx.x;
  int node = gid >> 3;
  int q = gid & 7;
  if (node >= N_NODES) return;
  const uint4* gp4 = (const uint4*)gb;
  int i = start[node];
  const int e1 = start[node + 1];
  float acc[8];
#pragma unroll
  for (int j = 0; j < 8; ++j) acc[j] = 0.f;
  for (; i + 4 <= e1; i += 4) {
    int s0 = esrc[i];
    int s1 = esrc[i + 1];
    int s2 = esrc[i + 2];
    int s3 = esrc[i + 3];
    uint4 u0 = gp4[(size_t)s0 * 8 + q];
    uint4 u1 = gp4[(size_t)s1 * 8 + q];
    uint4 u2 = gp4[(size_t)s2 * 8 + q];
    uint4 u3 = gp4[(size_t)s3 * 8 + q];
    add8(acc, u0);
    add8(acc, u1);
    add8(acc, u2);
    add8(acc, u3);
  }
  for (; i < e1; ++i) {
    uint4 u = gp4[(size_t)esrc[i] * 8 + q];
    add8(acc, u);
  }
  uint4 us = gp4[(size_t)node * 8 + q];
  add8(acc, us);                           // self (pre-scaled)
  // classes live in quads q<5 (cols 0..39); q>=5 quads are zeros by construction
  const bool wr = q < 5;
  float v0 = 0.f, v1 = 0.f, v2 = 0.f, v3 = 0.f, v4 = 0.f, v5 = 0.f, v6 = 0.f, v7 = 0.f;
  float m = -INFINITY;
  if (wr) {
    float d = dis[node];
    float4 ba = *(const float4*)&b2[q * 8];
    float4 bb = *(const float4*)&b2[q * 8 + 4];
    v0 = d * acc[0] + ba.x;
    v1 = d * acc[1] + ba.y;
    v2 = d * acc[2] + ba.z;
    v3 = d * acc[3] + ba.w;
    v4 = d * acc[4] + bb.x;
    v5 = d * acc[5] + bb.y;
    v6 = d * acc[6] + bb.z;
    v7 = d * acc[7] + bb.w;
    m = fmaxf(fmaxf(fmaxf(v0, v1), fmaxf(v2, v3)),
              fmaxf(fmaxf(v4, v5), fmaxf(v6, v7)));
  }
  // reduce max/sum within the 8-lane group (offsets 1,2,4 stay inside group)
#pragma unroll
  for (int off = 1; off < 8; off <<= 1) m = fmaxf(m, __shfl_xor(m, off));
  float el = 0.f;
  if (wr) {
    el = __expf(v0 - m) + __expf(v1 - m) + __expf(v2 - m) + __expf(v3 - m) +
         __expf(v4 - m) + __expf(v5 - m) + __expf(v6 - m) + __expf(v7 - m);
  }
#pragma unroll
  for (int off = 1; off < 8; off <<= 1) el += __shfl_xor(el, off);
  float ls = logf(el);
  if (wr) {
    float4 o1 = make_float4(v0 - m - ls, v1 - m - ls, v2 - m - ls, v3 - m - ls);
    float4 o2 = make_float4(v4 - m - ls, v5 - m - ls, v6 - m - ls, v7 - m - ls);
    *(float4*)&out[(size_t)node * NCLS + q * 8] = o1;
    *(float4*)&out[(size_t)node * NCLS + q * 8 + 4] = o2;
  }
}

// ---------------- launch ----------------

extern "C" void kernel_launch(void* const* d_in, const int* in_sizes, int n_in,
                              void* d_out, int out_size, void* d_ws, size_t ws_size,
                              hipStream_t stream) {
  const float* x  = (const float*)d_in[0];
  const int*   ei = (const int*)d_in[1];
  const float* W1 = (const float*)d_in[2];
  const float* b1 = (const float*)d_in[3];
  const float* W2 = (const float*)d_in[4];
  const float* b2 = (const float*)d_in[5];
  float* out = (float*)d_out;

  const int* row = ei;             // edge_index[0] = src
  const int* col = ei + N_EDGES;   // edge_index[1] = dst

  // workspace layout (~41 MB)
  int*            esrc    = (int*)d_ws;                            // E ints     (6.4 MB)
  unsigned int*   bktdata = (unsigned int*)(esrc + N_EDGES);       // NBKT*CAP   (8.0 MB)
  unsigned short* h1b     = (unsigned short*)(bktdata + (size_t)NBKT * BKT_CAP); // 12.8 MB
  unsigned short* ab      = h1b + (size_t)N_NODES * HID;           // N*64 bf16  (12.8 MB)
  float*          dis     = (float*)(ab + (size_t)N_NODES * HID);  // N
  int*            start   = (int*)(dis + N_NODES);                 // N+1
  int*            gcur    = start + N_NODES + 1;                   // NBKT
  unsigned short* gb      = h1b;                                   // N*64 bf16, reuse

  k_zero<<<1, 256, 0, stream>>>(gcur);
  k_binA<<<(N_EDGES + EPB - 1) / EPB, 256, 0, stream>>>(row, col, gcur, bktdata);
  k_build2<<<NBKT, 256, 0, stream>>>(gcur, bktdata, dis, start, esrc);

  k_gemm1<<<(N_NODES + 63) / 64, 256, 0, stream>>>(x, W1, dis, h1b);
  k_agg1<<<(N_NODES * 8 + 255) / 256, 256, 0, stream>>>(esrc, start, dis, h1b, b1, ab);

  k_gemm2<<<(N_NODES + 63) / 64, 256, 0, stream>>>(ab, W2, dis, gb);
  k_agg2ls<<<(N_NODES * 8 + 255) / 256, 256, 0, stream>>>(esrc, start, dis, gb, b2, out);
}

// Round 12
// 304.293 us; speedup vs baseline: 1.3453x; 1.0394x over previous
//
#include <hip/hip_runtime.h>
#include <math.h>

#define N_NODES 100000
#define N_EDGES 1600000
#define F_INDIM 256
#define HID 64
#define NCLS 40
#define NBKT 196         // ceil(N_NODES/512) coarse buckets of 512 dst nodes
#define BKT_CAP 10240    // per-bucket capacity (mean 8192 for uniform graph)
#define EPB 8192         // edges per block in k_binA
#define ESRC_CAP 1904640 // E + NBKT*(1536+4), rounded to mult of 4

typedef __attribute__((ext_vector_type(8))) short short8;
typedef __attribute__((ext_vector_type(4))) float floatx4;

// ---- bf16 helpers (RNE) ----
__device__ __forceinline__ unsigned short f2bf(float f) {
  unsigned u = __float_as_uint(f);
  unsigned r = (u + 0x7FFFu + ((u >> 16) & 1u)) >> 16;
  return (unsigned short)r;
}
// accumulate 8 packed bf16 (one 16B quad of a row) into 8 fp32 accumulators
__device__ __forceinline__ void add8(float* a, uint4 u) {
  a[0] += __uint_as_float(u.x << 16);
  a[1] += __uint_as_float(u.x & 0xFFFF0000u);
  a[2] += __uint_as_float(u.y << 16);
  a[3] += __uint_as_float(u.y & 0xFFFF0000u);
  a[4] += __uint_as_float(u.z << 16);
  a[5] += __uint_as_float(u.z & 0xFFFF0000u);
  a[6] += __uint_as_float(u.w << 16);
  a[7] += __uint_as_float(u.w & 0xFFFF0000u);
}

// ---------------- tiny init: zero bucket cursors + dummy row of h1b ----------------

__global__ __launch_bounds__(256) void k_zero(int* __restrict__ gcur,
                                              unsigned int* __restrict__ h1bw) {
  int t = threadIdx.x;
  if (t < NBKT) gcur[t] = 0;
  if (t < 32) h1bw[(size_t)N_NODES * 32 + t] = 0;   // zero row N_NODES (128 B)
}

// ---------------- phase A: coarse-bucket edges, clustered writes ----------------
// int4-vectorized edge reads (EPB and N_EDGES are multiples of 4).

__global__ __launch_bounds__(256) void k_binA(const int* __restrict__ row,
                                              const int* __restrict__ col,
                                              int* __restrict__ gcur,
                                              unsigned int* __restrict__ bktdata) {
  __shared__ int hist[NBKT];
  __shared__ int cur[NBKT];
  __shared__ int gbase[NBKT];
  const int t = threadIdx.x;
  const int e0 = blockIdx.x * EPB;
  const int n = min(EPB, N_EDGES - e0);
  if (t < NBKT) hist[t] = 0;
  __syncthreads();
  for (int i = t * 4; i < n; i += 1024) {
    int4 c4 = *(const int4*)&col[e0 + i];
    atomicAdd(&hist[c4.x >> 9], 1);
    atomicAdd(&hist[c4.y >> 9], 1);
    atomicAdd(&hist[c4.z >> 9], 1);
    atomicAdd(&hist[c4.w >> 9], 1);
  }
  __syncthreads();
  if (t < NBKT) {
    cur[t] = 0;
    int h = hist[t];
    gbase[t] = (h > 0) ? atomicAdd(&gcur[t], h) : 0;
  }
  __syncthreads();
  for (int i = t * 4; i < n; i += 1024) {
    int4 c4 = *(const int4*)&col[e0 + i];
    int4 r4 = *(const int4*)&row[e0 + i];
#pragma unroll
    for (int k = 0; k < 4; ++k) {
      int c = (k == 0) ? c4.x : (k == 1) ? c4.y : (k == 2) ? c4.z : c4.w;
      int r = (k == 0) ? r4.x : (k == 1) ? r4.y : (k == 2) ? r4.z : r4.w;
      int b = c >> 9;
      int p = atomicAdd(&cur[b], 1);
      bktdata[(size_t)b * BKT_CAP + gbase[b] + p] =
          ((unsigned)(c & 511) << 17) | (unsigned)r;
    }
  }
}

// ---------------- phase B (fused): hist + dis + padded scan + placement ----------
// Segments padded to multiples of 4 (padding slots = dummy node N_NODES).
// Bucket region b: base = sum_{j<b} ((gcur[j]+3)&~3 + 1536)  (4-aligned).

__global__ __launch_bounds__(256) void k_build2(const int* __restrict__ gcur,
                                                const unsigned int* __restrict__ bktdata,
                                                float* __restrict__ dis,
                                                int* __restrict__ start,
                                                int* __restrict__ endi,
                                                int* __restrict__ esrc) {
  __shared__ int h[512];
  __shared__ int cur[512];
  __shared__ int sbase[512];
  __shared__ int wsum[4];
  const int b = blockIdx.x, t = threadIdx.x;
  h[t] = 0; h[t + 256] = 0; cur[t] = 0; cur[t + 256] = 0;
  // padded base for this bucket
  int pv = (t < b) ? (((gcur[t] + 3) & ~3) + 1536) : 0;
#pragma unroll
  for (int off = 1; off < 64; off <<= 1) pv += __shfl_xor(pv, off);
  if ((t & 63) == 0) wsum[t >> 6] = pv;
  __syncthreads();
  const int base = wsum[0] + wsum[1] + wsum[2] + wsum[3];

  const int cnt = gcur[b];
  const unsigned int* p = bktdata + (size_t)b * BKT_CAP;
  for (int i = t; i < cnt; i += 256) atomicAdd(&h[p[i] >> 17], 1);
  __syncthreads();

  const int n0 = b * 512 + t, n1 = n0 + 256;
  const int c0 = h[t], c1 = h[t + 256];
  const int p0 = (c0 + 3) & ~3, p1 = (c1 + 3) & ~3;
  if (n0 < N_NODES) dis[n0] = rsqrtf((float)(c0 + 1));
  if (n1 < N_NODES) dis[n1] = rsqrtf((float)(c1 + 1));
  h[t] = p0; h[t + 256] = p1;            // scan PADDED counts
  __syncthreads();
  // inclusive Hillis-Steele over 512 entries (2 per thread)
#pragma unroll
  for (int off = 1; off < 512; off <<= 1) {
    int u0 = (t >= off) ? h[t - off] : 0;
    int u1 = ((t + 256) >= off) ? h[t + 256 - off] : 0;
    __syncthreads();
    h[t] += u0; h[t + 256] += u1;
    __syncthreads();
  }
  const int sb0 = base + h[t] - p0;       // exclusive padded start (4-aligned)
  const int sb1 = base + h[t + 256] - p1;
  sbase[t] = sb0; sbase[t + 256] = sb1;
  if (n0 < N_NODES) { start[n0] = sb0; endi[n0] = sb0 + c0; }
  if (n1 < N_NODES) { start[n1] = sb1; endi[n1] = sb1 + c1; }
  // fill padding slots with dummy node (zero row)
  for (int k = c0; k < p0; ++k) esrc[sb0 + k] = N_NODES;
  for (int k = c1; k < p1; ++k) esrc[sb1 + k] = N_NODES;
  __syncthreads();

  for (int i = t; i < cnt; i += 256) {
    unsigned u = p[i];
    int ld = u >> 17;
    int src = u & 0x1FFFF;
    int pos = sbase[ld] + atomicAdd(&cur[ld], 1);
    esrc[pos] = src;
  }
}

// ---------------- GEMM1 (MFMA): h1b = bf16(dis[row] * (x @ W1)) ----------------
// A-fragments direct from global (x has zero cross-block reuse); W1^T in LDS.

#define KP 264   // padded k-stride for wt (2-way bank aliasing only = free)

__global__ __launch_bounds__(256) void k_gemm1(const float* __restrict__ x,
                                               const float* __restrict__ W1,
                                               const float* __restrict__ dis,
                                               unsigned short* __restrict__ h1b) {
  __shared__ unsigned short wt[HID * KP];   // wt[n][k] = bf16(W1[k][n])
  const int tid = threadIdx.x;
  const int lane = tid & 63;
  const int w = tid >> 6;
  const int quad = lane >> 4;
  const int l15 = lane & 15;
  const int rowBase = blockIdx.x * 64;

#pragma unroll
  for (int i = 0; i < 16; ++i) {
    int f = tid + 256 * i;
    int k = f >> 4;
    int n0 = (f & 15) * 4;
    float4 v = *(const float4*)&W1[(size_t)k * HID + n0];
    wt[(n0 + 0) * KP + k] = f2bf(v.x);
    wt[(n0 + 1) * KP + k] = f2bf(v.y);
    wt[(n0 + 2) * KP + k] = f2bf(v.z);
    wt[(n0 + 3) * KP + k] = f2bf(v.w);
  }
  __syncthreads();

  const int ar = rowBase + w * 16 + l15;
  const float* xrow = x + (size_t)((ar < N_NODES) ? ar : N_NODES - 1) * F_INDIM + quad * 8;

  floatx4 acc[4];
#pragma unroll
  for (int c = 0; c < 4; ++c) acc[c] = (floatx4){0.f, 0.f, 0.f, 0.f};

#pragma unroll
  for (int kc = 0; kc < F_INDIM; kc += 32) {
    const float4 va = *(const float4*)(xrow + kc);
    const float4 vb = *(const float4*)(xrow + kc + 4);
    short8 a;
    a[0] = (short)f2bf(va.x); a[1] = (short)f2bf(va.y);
    a[2] = (short)f2bf(va.z); a[3] = (short)f2bf(va.w);
    a[4] = (short)f2bf(vb.x); a[5] = (short)f2bf(vb.y);
    a[6] = (short)f2bf(vb.z); a[7] = (short)f2bf(vb.w);
#pragma unroll
    for (int c = 0; c < 4; ++c) {
      const short8 b = *(const short8*)&wt[(c * 16 + l15) * KP + kc + quad * 8];
      acc[c] = __builtin_amdgcn_mfma_f32_16x16x32_bf16(a, b, acc[c], 0, 0, 0);
    }
  }

#pragma unroll
  for (int reg = 0; reg < 4; ++reg) {
    int gr = rowBase + w * 16 + quad * 4 + reg;
    if (gr < N_NODES) {
      float d = dis[gr];
#pragma unroll
      for (int c = 0; c < 4; ++c)
        h1b[(size_t)gr * HID + c * 16 + l15] = f2bf(d * acc[c][reg]);
    }
  }
}

// ---------------- agg1: ab = bf16(relu(dis[n]*(self+sum) + b1)) ----------------
// one node per 8-lane group; segments 4-padded -> int4 esrc loads, no remainder.

__global__ __launch_bounds__(256) void k_agg1(const int* __restrict__ esrc,
                                              const int* __restrict__ start,
                                              const int* __restrict__ endi,
                                              const float* __restrict__ dis,
                                              const unsigned short* __restrict__ h1b,
                                              const float* __restrict__ b1,
                                              unsigned short* __restrict__ ab) {
  int gid = blockIdx.x * 256 + threadIdx.x;
  int node = gid >> 3;
  int q = gid & 7;
  if (node >= N_NODES) return;
  const uint4* hp4 = (const uint4*)h1b;    // row = 8 quads of 16B
  const int s = start[node];
  const int epad = (endi[node] + 3) & ~3;
  float acc[8];
#pragma unroll
  for (int j = 0; j < 8; ++j) acc[j] = 0.f;
  for (int i = s; i < epad; i += 4) {
    int4 sv = *(const int4*)&esrc[i];
    uint4 u0 = hp4[(size_t)sv.x * 8 + q];
    uint4 u1 = hp4[(size_t)sv.y * 8 + q];
    uint4 u2 = hp4[(size_t)sv.z * 8 + q];
    uint4 u3 = hp4[(size_t)sv.w * 8 + q];
    add8(acc, u0);
    add8(acc, u1);
    add8(acc, u2);
    add8(acc, u3);
  }
  uint4 us = hp4[(size_t)node * 8 + q];
  add8(acc, us);                           // self term (pre-scaled)
  float d = dis[node];
  float4 ba = *(const float4*)&b1[q * 8];
  float4 bb = *(const float4*)&b1[q * 8 + 4];
  float v0 = fmaxf(d * acc[0] + ba.x, 0.f);
  float v1 = fmaxf(d * acc[1] + ba.y, 0.f);
  float v2 = fmaxf(d * acc[2] + ba.z, 0.f);
  float v3 = fmaxf(d * acc[3] + ba.w, 0.f);
  float v4 = fmaxf(d * acc[4] + bb.x, 0.f);
  float v5 = fmaxf(d * acc[5] + bb.y, 0.f);
  float v6 = fmaxf(d * acc[6] + bb.z, 0.f);
  float v7 = fmaxf(d * acc[7] + bb.w, 0.f);
  uint4 o;
  o.x = (unsigned)f2bf(v0) | ((unsigned)f2bf(v1) << 16);
  o.y = (unsigned)f2bf(v2) | ((unsigned)f2bf(v3) << 16);
  o.z = (unsigned)f2bf(v4) | ((unsigned)f2bf(v5) << 16);
  o.w = (unsigned)f2bf(v6) | ((unsigned)f2bf(v7) << 16);
  ((uint4*)ab)[(size_t)node * 8 + q] = o;
}

// ---------------- GEMM2 (MFMA): gb = bf16(dis[row] * (ab @ W2)), rows padded 64 ----

#define AP 72    // padded k-stride

__global__ __launch_bounds__(256) void k_gemm2(const unsigned short* __restrict__ ab,
                                               const float* __restrict__ W2,
                                               const float* __restrict__ dis,
                                               unsigned short* __restrict__ gb) {
  __shared__ unsigned short as[64 * AP];
  __shared__ unsigned short w2t[48 * AP];   // w2t[n][k] = bf16(W2[k][n]), 0-pad n>=40
  const int tid = threadIdx.x;
  const int lane = tid & 63;
  const int w = tid >> 6;
  const int quad = lane >> 4;
  const int l15 = lane & 15;
  const int rowBase = blockIdx.x * 64;

  for (int i = tid; i < 48 * 64; i += 256) {
    int n = i >> 6;
    int k = i & 63;
    w2t[n * AP + k] = (n < NCLS) ? f2bf(W2[(size_t)k * NCLS + n]) : (unsigned short)0;
  }
#pragma unroll
  for (int i = 0; i < 2; ++i) {
    int f = tid + 256 * i;
    int r = f >> 3;
    int q = f & 7;
    int gr = rowBase + r;
    short8 v = (short8){0, 0, 0, 0, 0, 0, 0, 0};
    if (gr < N_NODES) v = *(const short8*)&ab[(size_t)gr * HID + q * 8];
    *(short8*)&as[r * AP + q * 8] = v;
  }
  __syncthreads();

  floatx4 acc[3];
#pragma unroll
  for (int c = 0; c < 3; ++c) acc[c] = (floatx4){0.f, 0.f, 0.f, 0.f};

#pragma unroll
  for (int kh = 0; kh < 2; ++kh) {
    const short8 a = *(const short8*)&as[(w * 16 + l15) * AP + kh * 32 + quad * 8];
#pragma unroll
    for (int c = 0; c < 3; ++c) {
      const short8 b = *(const short8*)&w2t[(c * 16 + l15) * AP + kh * 32 + quad * 8];
      acc[c] = __builtin_amdgcn_mfma_f32_16x16x32_bf16(a, b, acc[c], 0, 0, 0);
    }
  }

#pragma unroll
  for (int reg = 0; reg < 4; ++reg) {
    int gr = rowBase + w * 16 + quad * 4 + reg;
    if (gr < N_NODES) {
      float d = dis[gr];
#pragma unroll
      for (int c = 0; c < 3; ++c) {
        int cc = c * 16 + l15;   // cols 0..47 (40..47 genuinely zero via padded W2)
        gb[(size_t)gr * 64 + cc] = f2bf(d * acc[c][reg]);
      }
      gb[(size_t)gr * 64 + 48 + l15] = 0;   // zero cols 48..63 for full-row gathers
    }
  }
}

// ---------------- agg2 + log_softmax fused: one node per 8-lane group ----------

__global__ __launch_bounds__(256) void k_agg2ls(const int* __restrict__ esrc,
                                                const int* __restrict__ start,
                                                const int* __restrict__ endi,
                                                const float* __restrict__ dis,
                                                const unsigned short* __restrict__ gb,
                                                const float* __restrict__ b2,
                                                float* __restrict__ out) {
  int gid = blockIdx.x * 256 + threadIdx.x;
  int node = gid >> 3;
  int q = gid & 7;
  if (node >= N_NODES) return;
  const uint4* gp4 = (const uint4*)gb;
  const int s = start[node];
  const int epad = (endi[node] + 3) & ~3;
  float acc[8];
#pragma unroll
  for (int j = 0; j < 8; ++j) acc[j] = 0.f;
  for (int i = s; i < epad; i += 4) {
    int4 sv = *(const int4*)&esrc[i];
    uint4 u0 = gp4[(size_t)sv.x * 8 + q];
    uint4 u1 = gp4[(size_t)sv.y * 8 + q];
    uint4 u2 = gp4[(size_t)sv.z * 8 + q];
    uint4 u3 = gp4[(size_t)sv.w * 8 + q];
    add8(acc, u0);
    add8(acc, u1);
    add8(acc, u2);
    add8(acc, u3);
  }
  uint4 us = gp4[(size_t)node * 8 + q];
  add8(acc, us);                           // self (pre-scaled)
  // classes live in quads q<5 (cols 0..39); q>=5 quads are zeros by construction
  const bool wr = q < 5;
  float v0 = 0.f, v1 = 0.f, v2 = 0.f, v3 = 0.f, v4 = 0.f, v5 = 0.f, v6 = 0.f, v7 = 0.f;
  float m = -INFINITY;
  if (wr) {
    float d = dis[node];
    float4 ba = *(const float4*)&b2[q * 8];
    float4 bb = *(const float4*)&b2[q * 8 + 4];
    v0 = d * acc[0] + ba.x;
    v1 = d * acc[1] + ba.y;
    v2 = d * acc[2] + ba.z;
    v3 = d * acc[3] + ba.w;
    v4 = d * acc[4] + bb.x;
    v5 = d * acc[5] + bb.y;
    v6 = d * acc[6] + bb.z;
    v7 = d * acc[7] + bb.w;
    m = fmaxf(fmaxf(fmaxf(v0, v1), fmaxf(v2, v3)),
              fmaxf(fmaxf(v4, v5), fmaxf(v6, v7)));
  }
  // reduce max/sum within the 8-lane group (offsets 1,2,4 stay inside group)
#pragma unroll
  for (int off = 1; off < 8; off <<= 1) m = fmaxf(m, __shfl_xor(m, off));
  float el = 0.f;
  if (wr) {
    el = __expf(v0 - m) + __expf(v1 - m) + __expf(v2 - m) + __expf(v3 - m) +
         __expf(v4 - m) + __expf(v5 - m) + __expf(v6 - m) + __expf(v7 - m);
  }
#pragma unroll
  for (int off = 1; off < 8; off <<= 1) el += __shfl_xor(el, off);
  float ls = logf(el);
  if (wr) {
    float4 o1 = make_float4(v0 - m - ls, v1 - m - ls, v2 - m - ls, v3 - m - ls);
    float4 o2 = make_float4(v4 - m - ls, v5 - m - ls, v6 - m - ls, v7 - m - ls);
    *(float4*)&out[(size_t)node * NCLS + q * 8] = o1;
    *(float4*)&out[(size_t)node * NCLS + q * 8 + 4] = o2;
  }
}

// ---------------- launch ----------------

extern "C" void kernel_launch(void* const* d_in, const int* in_sizes, int n_in,
                              void* d_out, int out_size, void* d_ws, size_t ws_size,
                              hipStream_t stream) {
  const float* x  = (const float*)d_in[0];
  const int*   ei = (const int*)d_in[1];
  const float* W1 = (const float*)d_in[2];
  const float* b1 = (const float*)d_in[3];
  const float* W2 = (const float*)d_in[4];
  const float* b2 = (const float*)d_in[5];
  float* out = (float*)d_out;

  const int* row = ei;             // edge_index[0] = src
  const int* col = ei + N_EDGES;   // edge_index[1] = dst

  // workspace layout (~43 MB)
  int*            esrc    = (int*)d_ws;                            // ESRC_CAP ints (7.6 MB)
  unsigned int*   bktdata = (unsigned int*)(esrc + ESRC_CAP);      // NBKT*CAP      (8.0 MB)
  unsigned short* h1b     = (unsigned short*)(bktdata + (size_t)NBKT * BKT_CAP); // (N+1)*64 bf16
  unsigned short* ab      = h1b + (size_t)(N_NODES + 1) * HID;     // N*64 bf16   (12.8 MB)
  float*          dis     = (float*)(ab + (size_t)N_NODES * HID);  // N
  int*            start   = (int*)(dis + N_NODES);                 // N+1
  int*            endi    = start + N_NODES + 1;                   // N
  int*            gcur    = endi + N_NODES;                        // NBKT
  unsigned short* gb      = h1b;                                   // (N+1)*64 bf16, reuse

  k_zero<<<1, 256, 0, stream>>>(gcur, (unsigned int*)h1b);
  k_binA<<<(N_EDGES + EPB - 1) / EPB, 256, 0, stream>>>(row, col, gcur, bktdata);
  k_build2<<<NBKT, 256, 0, stream>>>(gcur, bktdata, dis, start, endi, esrc);

  k_gemm1<<<(N_NODES + 63) / 64, 256, 0, stream>>>(x, W1, dis, h1b);
  k_agg1<<<(N_NODES * 8 + 255) / 256, 256, 0, stream>>>(esrc, start, endi, dis, h1b, b1, ab);

  k_gemm2<<<(N_NODES + 63) / 64, 256, 0, stream>>>(ab, W2, dis, gb);
  k_agg2ls<<<(N_NODES * 8 + 255) / 256, 256, 0, stream>>>(esrc, start, endi, dis, gb, b2, out);
}

// Round 13
// 290.424 us; speedup vs baseline: 1.4095x; 1.0478x over previous
//
#include <hip/hip_runtime.h>
#include <math.h>

#define N_NODES 100000
#define N_EDGES 1600000
#define F_INDIM 256
#define HID 64
#define NCLS 40
#define NBKT 196         // ceil(N_NODES/512) coarse buckets of 512 dst nodes
#define BKT_CAP 10240    // per-bucket capacity (mean 8192 for uniform graph)
#define EPB 8192         // edges per block in k_binA
#define ESRC_CAP 1904640 // E + NBKT*(1536+4), rounded to mult of 4

typedef __attribute__((ext_vector_type(8))) short short8;
typedef __attribute__((ext_vector_type(4))) float floatx4;

// ---- bf16 helpers (RNE) ----
__device__ __forceinline__ unsigned short f2bf(float f) {
  unsigned u = __float_as_uint(f);
  unsigned r = (u + 0x7FFFu + ((u >> 16) & 1u)) >> 16;
  return (unsigned short)r;
}
// accumulate 8 packed bf16 (one 16B quad of a row) into 8 fp32 accumulators
__device__ __forceinline__ void add8(float* a, uint4 u) {
  a[0] += __uint_as_float(u.x << 16);
  a[1] += __uint_as_float(u.x & 0xFFFF0000u);
  a[2] += __uint_as_float(u.y << 16);
  a[3] += __uint_as_float(u.y & 0xFFFF0000u);
  a[4] += __uint_as_float(u.z << 16);
  a[5] += __uint_as_float(u.z & 0xFFFF0000u);
  a[6] += __uint_as_float(u.w << 16);
  a[7] += __uint_as_float(u.w & 0xFFFF0000u);
}

// ---------------- tiny init: zero bucket cursors + dummy row of h1b ----------------

__global__ __launch_bounds__(256) void k_zero(int* __restrict__ gcur,
                                              unsigned int* __restrict__ h1bw) {
  int t = threadIdx.x;
  if (t < NBKT) gcur[t] = 0;
  if (t < 32) h1bw[(size_t)N_NODES * 32 + t] = 0;   // zero row N_NODES (128 B)
}

// ---------------- phase A: coarse-bucket edges, clustered writes ----------------
// 1024 threads/block (16 waves/CU at grid=196=1 block/CU) to hide LDS-atomic
// and load latency; int4-vectorized edge reads.

__global__ __launch_bounds__(1024) void k_binA(const int* __restrict__ row,
                                               const int* __restrict__ col,
                                               int* __restrict__ gcur,
                                               unsigned int* __restrict__ bktdata) {
  __shared__ int hist[NBKT];
  __shared__ int cur[NBKT];
  __shared__ int gbase[NBKT];
  const int t = threadIdx.x;
  const int e0 = blockIdx.x * EPB;
  const int n = min(EPB, N_EDGES - e0);
  if (t < NBKT) hist[t] = 0;
  __syncthreads();
  for (int i = t * 4; i < n; i += 4096) {
    int4 c4 = *(const int4*)&col[e0 + i];
    atomicAdd(&hist[c4.x >> 9], 1);
    atomicAdd(&hist[c4.y >> 9], 1);
    atomicAdd(&hist[c4.z >> 9], 1);
    atomicAdd(&hist[c4.w >> 9], 1);
  }
  __syncthreads();
  if (t < NBKT) {
    cur[t] = 0;
    int h = hist[t];
    gbase[t] = (h > 0) ? atomicAdd(&gcur[t], h) : 0;
  }
  __syncthreads();
  for (int i = t * 4; i < n; i += 4096) {
    int4 c4 = *(const int4*)&col[e0 + i];
    int4 r4 = *(const int4*)&row[e0 + i];
#pragma unroll
    for (int k = 0; k < 4; ++k) {
      int c = (k == 0) ? c4.x : (k == 1) ? c4.y : (k == 2) ? c4.z : c4.w;
      int r = (k == 0) ? r4.x : (k == 1) ? r4.y : (k == 2) ? r4.z : r4.w;
      int b = c >> 9;
      int p = atomicAdd(&cur[b], 1);
      bktdata[(size_t)b * BKT_CAP + gbase[b] + p] =
          ((unsigned)(c & 511) << 17) | (unsigned)r;
    }
  }
}

// ---------------- phase B (fused): hist + dis + padded scan + placement ----------
// 1024 threads/block; segments padded to multiples of 4 (pad = dummy node).

__global__ __launch_bounds__(1024) void k_build2(const int* __restrict__ gcur,
                                                 const unsigned int* __restrict__ bktdata,
                                                 float* __restrict__ dis,
                                                 int* __restrict__ start,
                                                 int* __restrict__ endi,
                                                 int* __restrict__ esrc) {
  __shared__ int h[512];
  __shared__ int cur[512];
  __shared__ int sbase[512];
  __shared__ int wsum[4];
  const int b = blockIdx.x, t = threadIdx.x;
  if (t < 512) { h[t] = 0; cur[t] = 0; }
  // padded base for this bucket (threads 0..255 compute it)
  if (t < 256) {
    int pv = (t < b) ? (((gcur[t] + 3) & ~3) + 1536) : 0;
#pragma unroll
    for (int off = 1; off < 64; off <<= 1) pv += __shfl_xor(pv, off);
    if ((t & 63) == 0) wsum[t >> 6] = pv;
  }
  __syncthreads();
  const int base = wsum[0] + wsum[1] + wsum[2] + wsum[3];

  const int cnt = gcur[b];
  const unsigned int* p = bktdata + (size_t)b * BKT_CAP;
  for (int i = t; i < cnt; i += 1024) atomicAdd(&h[p[i] >> 17], 1);
  __syncthreads();

  int c0 = 0, p0 = 0;
  if (t < 512) {
    const int n0 = b * 512 + t;
    c0 = h[t];
    p0 = (c0 + 3) & ~3;
    if (n0 < N_NODES) dis[n0] = rsqrtf((float)(c0 + 1));
    h[t] = p0;                           // scan PADDED counts
  }
  __syncthreads();
  // inclusive Hillis-Steele over 512 entries (first 512 threads)
#pragma unroll
  for (int off = 1; off < 512; off <<= 1) {
    int u = (t < 512 && t >= off) ? h[t - off] : 0;
    __syncthreads();
    if (t < 512) h[t] += u;
    __syncthreads();
  }
  if (t < 512) {
    const int n0 = b * 512 + t;
    const int sb0 = base + h[t] - p0;    // exclusive padded start (4-aligned)
    sbase[t] = sb0;
    if (n0 < N_NODES) { start[n0] = sb0; endi[n0] = sb0 + c0; }
    for (int k = c0; k < p0; ++k) esrc[sb0 + k] = N_NODES;   // dummy fill
    if (b == 0 && t == 0) start[N_NODES] = N_EDGES;          // sentinel (unused)
  }
  __syncthreads();

  for (int i = t; i < cnt; i += 1024) {
    unsigned u = p[i];
    int ld = u >> 17;
    int src = u & 0x1FFFF;
    int pos = sbase[ld] + atomicAdd(&cur[ld], 1);
    esrc[pos] = src;
  }
}

// ---------------- GEMM1 (MFMA): h1b = bf16(dis[row] * (x @ W1)) ----------------
// A-fragments direct from global (x has zero cross-block reuse); W1^T in LDS.

#define KP 264   // padded k-stride for wt (2-way bank aliasing only = free)

__global__ __launch_bounds__(256) void k_gemm1(const float* __restrict__ x,
                                               const float* __restrict__ W1,
                                               const float* __restrict__ dis,
                                               unsigned short* __restrict__ h1b) {
  __shared__ unsigned short wt[HID * KP];   // wt[n][k] = bf16(W1[k][n])
  const int tid = threadIdx.x;
  const int lane = tid & 63;
  const int w = tid >> 6;
  const int quad = lane >> 4;
  const int l15 = lane & 15;
  const int rowBase = blockIdx.x * 64;

#pragma unroll
  for (int i = 0; i < 16; ++i) {
    int f = tid + 256 * i;
    int k = f >> 4;
    int n0 = (f & 15) * 4;
    float4 v = *(const float4*)&W1[(size_t)k * HID + n0];
    wt[(n0 + 0) * KP + k] = f2bf(v.x);
    wt[(n0 + 1) * KP + k] = f2bf(v.y);
    wt[(n0 + 2) * KP + k] = f2bf(v.z);
    wt[(n0 + 3) * KP + k] = f2bf(v.w);
  }
  __syncthreads();

  const int ar = rowBase + w * 16 + l15;
  const float* xrow = x + (size_t)((ar < N_NODES) ? ar : N_NODES - 1) * F_INDIM + quad * 8;

  floatx4 acc[4];
#pragma unroll
  for (int c = 0; c < 4; ++c) acc[c] = (floatx4){0.f, 0.f, 0.f, 0.f};

#pragma unroll
  for (int kc = 0; kc < F_INDIM; kc += 32) {
    const float4 va = *(const float4*)(xrow + kc);
    const float4 vb = *(const float4*)(xrow + kc + 4);
    short8 a;
    a[0] = (short)f2bf(va.x); a[1] = (short)f2bf(va.y);
    a[2] = (short)f2bf(va.z); a[3] = (short)f2bf(va.w);
    a[4] = (short)f2bf(vb.x); a[5] = (short)f2bf(vb.y);
    a[6] = (short)f2bf(vb.z); a[7] = (short)f2bf(vb.w);
#pragma unroll
    for (int c = 0; c < 4; ++c) {
      const short8 b = *(const short8*)&wt[(c * 16 + l15) * KP + kc + quad * 8];
      acc[c] = __builtin_amdgcn_mfma_f32_16x16x32_bf16(a, b, acc[c], 0, 0, 0);
    }
  }

#pragma unroll
  for (int reg = 0; reg < 4; ++reg) {
    int gr = rowBase + w * 16 + quad * 4 + reg;
    if (gr < N_NODES) {
      float d = dis[gr];
#pragma unroll
      for (int c = 0; c < 4; ++c)
        h1b[(size_t)gr * HID + c * 16 + l15] = f2bf(d * acc[c][reg]);
    }
  }
}

// ---------------- agg1: ab = bf16(relu(dis[n]*(self+sum) + b1)) ----------------
// one node per 8-lane group; 8 edges in flight (2x int4 esrc + 8 row gathers).

__global__ __launch_bounds__(256) void k_agg1(const int* __restrict__ esrc,
                                              const int* __restrict__ start,
                                              const int* __restrict__ endi,
                                              const float* __restrict__ dis,
                                              const unsigned short* __restrict__ h1b,
                                              const float* __restrict__ b1,
                                              unsigned short* __restrict__ ab) {
  int gid = blockIdx.x * 256 + threadIdx.x;
  int node = gid >> 3;
  int q = gid & 7;
  if (node >= N_NODES) return;
  const uint4* hp4 = (const uint4*)h1b;    // row = 8 quads of 16B
  const int s = start[node];
  const int epad = (endi[node] + 3) & ~3;
  float acc[8];
#pragma unroll
  for (int j = 0; j < 8; ++j) acc[j] = 0.f;
  int i = s;
  for (; i + 8 <= epad; i += 8) {
    int4 sa = *(const int4*)&esrc[i];
    int4 sb = *(const int4*)&esrc[i + 4];
    uint4 u0 = hp4[(size_t)sa.x * 8 + q];
    uint4 u1 = hp4[(size_t)sa.y * 8 + q];
    uint4 u2 = hp4[(size_t)sa.z * 8 + q];
    uint4 u3 = hp4[(size_t)sa.w * 8 + q];
    uint4 u4 = hp4[(size_t)sb.x * 8 + q];
    uint4 u5 = hp4[(size_t)sb.y * 8 + q];
    uint4 u6 = hp4[(size_t)sb.z * 8 + q];
    uint4 u7 = hp4[(size_t)sb.w * 8 + q];
    add8(acc, u0); add8(acc, u1); add8(acc, u2); add8(acc, u3);
    add8(acc, u4); add8(acc, u5); add8(acc, u6); add8(acc, u7);
  }
  if (i < epad) {                          // exactly 4 remain
    int4 sv = *(const int4*)&esrc[i];
    uint4 u0 = hp4[(size_t)sv.x * 8 + q];
    uint4 u1 = hp4[(size_t)sv.y * 8 + q];
    uint4 u2 = hp4[(size_t)sv.z * 8 + q];
    uint4 u3 = hp4[(size_t)sv.w * 8 + q];
    add8(acc, u0); add8(acc, u1); add8(acc, u2); add8(acc, u3);
  }
  uint4 us = hp4[(size_t)node * 8 + q];
  add8(acc, us);                           // self term (pre-scaled)
  float d = dis[node];
  float4 ba = *(const float4*)&b1[q * 8];
  float4 bb = *(const float4*)&b1[q * 8 + 4];
  float v0 = fmaxf(d * acc[0] + ba.x, 0.f);
  float v1 = fmaxf(d * acc[1] + ba.y, 0.f);
  float v2 = fmaxf(d * acc[2] + ba.z, 0.f);
  float v3 = fmaxf(d * acc[3] + ba.w, 0.f);
  float v4 = fmaxf(d * acc[4] + bb.x, 0.f);
  float v5 = fmaxf(d * acc[5] + bb.y, 0.f);
  float v6 = fmaxf(d * acc[6] + bb.z, 0.f);
  float v7 = fmaxf(d * acc[7] + bb.w, 0.f);
  uint4 o;
  o.x = (unsigned)f2bf(v0) | ((unsigned)f2bf(v1) << 16);
  o.y = (unsigned)f2bf(v2) | ((unsigned)f2bf(v3) << 16);
  o.z = (unsigned)f2bf(v4) | ((unsigned)f2bf(v5) << 16);
  o.w = (unsigned)f2bf(v6) | ((unsigned)f2bf(v7) << 16);
  ((uint4*)ab)[(size_t)node * 8 + q] = o;
}

// ---------------- GEMM2 (MFMA): gb = bf16(dis[row] * (ab @ W2)), rows padded 64 ----

#define AP 72    // padded k-stride

__global__ __launch_bounds__(256) void k_gemm2(const unsigned short* __restrict__ ab,
                                               const float* __restrict__ W2,
                                               const float* __restrict__ dis,
                                               unsigned short* __restrict__ gb) {
  __shared__ unsigned short as[64 * AP];
  __shared__ unsigned short w2t[48 * AP];   // w2t[n][k] = bf16(W2[k][n]), 0-pad n>=40
  const int tid = threadIdx.x;
  const int lane = tid & 63;
  const int w = tid >> 6;
  const int quad = lane >> 4;
  const int l15 = lane & 15;
  const int rowBase = blockIdx.x * 64;

  for (int i = tid; i < 48 * 64; i += 256) {
    int n = i >> 6;
    int k = i & 63;
    w2t[n * AP + k] = (n < NCLS) ? f2bf(W2[(size_t)k * NCLS + n]) : (unsigned short)0;
  }
#pragma unroll
  for (int i = 0; i < 2; ++i) {
    int f = tid + 256 * i;
    int r = f >> 3;
    int q = f & 7;
    int gr = rowBase + r;
    short8 v = (short8){0, 0, 0, 0, 0, 0, 0, 0};
    if (gr < N_NODES) v = *(const short8*)&ab[(size_t)gr * HID + q * 8];
    *(short8*)&as[r * AP + q * 8] = v;
  }
  __syncthreads();

  floatx4 acc[3];
#pragma unroll
  for (int c = 0; c < 3; ++c) acc[c] = (floatx4){0.f, 0.f, 0.f, 0.f};

#pragma unroll
  for (int kh = 0; kh < 2; ++kh) {
    const short8 a = *(const short8*)&as[(w * 16 + l15) * AP + kh * 32 + quad * 8];
#pragma unroll
    for (int c = 0; c < 3; ++c) {
      const short8 b = *(const short8*)&w2t[(c * 16 + l15) * AP + kh * 32 + quad * 8];
      acc[c] = __builtin_amdgcn_mfma_f32_16x16x32_bf16(a, b, acc[c], 0, 0, 0);
    }
  }

#pragma unroll
  for (int reg = 0; reg < 4; ++reg) {
    int gr = rowBase + w * 16 + quad * 4 + reg;
    if (gr < N_NODES) {
      float d = dis[gr];
#pragma unroll
      for (int c = 0; c < 3; ++c) {
        int cc = c * 16 + l15;   // cols 0..47 (40..47 genuinely zero via padded W2)
        gb[(size_t)gr * 64 + cc] = f2bf(d * acc[c][reg]);
      }
      gb[(size_t)gr * 64 + 48 + l15] = 0;   // zero cols 48..63 for full-row gathers
    }
  }
}

// ---------------- agg2 + log_softmax fused: one node per 8-lane group ----------

__global__ __launch_bounds__(256) void k_agg2ls(const int* __restrict__ esrc,
                                                const int* __restrict__ start,
                                                const int* __restrict__ endi,
                                                const float* __restrict__ dis,
                                                const unsigned short* __restrict__ gb,
                                                const float* __restrict__ b2,
                                                float* __restrict__ out) {
  int gid = blockIdx.x * 256 + threadIdx.x;
  int node = gid >> 3;
  int q = gid & 7;
  if (node >= N_NODES) return;
  const uint4* gp4 = (const uint4*)gb;
  const int s = start[node];
  const int epad = (endi[node] + 3) & ~3;
  float acc[8];
#pragma unroll
  for (int j = 0; j < 8; ++j) acc[j] = 0.f;
  int i = s;
  for (; i + 8 <= epad; i += 8) {
    int4 sa = *(const int4*)&esrc[i];
    int4 sb = *(const int4*)&esrc[i + 4];
    uint4 u0 = gp4[(size_t)sa.x * 8 + q];
    uint4 u1 = gp4[(size_t)sa.y * 8 + q];
    uint4 u2 = gp4[(size_t)sa.z * 8 + q];
    uint4 u3 = gp4[(size_t)sa.w * 8 + q];
    uint4 u4 = gp4[(size_t)sb.x * 8 + q];
    uint4 u5 = gp4[(size_t)sb.y * 8 + q];
    uint4 u6 = gp4[(size_t)sb.z * 8 + q];
    uint4 u7 = gp4[(size_t)sb.w * 8 + q];
    add8(acc, u0); add8(acc, u1); add8(acc, u2); add8(acc, u3);
    add8(acc, u4); add8(acc, u5); add8(acc, u6); add8(acc, u7);
  }
  if (i < epad) {                          // exactly 4 remain
    int4 sv = *(const int4*)&esrc[i];
    uint4 u0 = gp4[(size_t)sv.x * 8 + q];
    uint4 u1 = gp4[(size_t)sv.y * 8 + q];
    uint4 u2 = gp4[(size_t)sv.z * 8 + q];
    uint4 u3 = gp4[(size_t)sv.w * 8 + q];
    add8(acc, u0); add8(acc, u1); add8(acc, u2); add8(acc, u3);
  }
  uint4 us = gp4[(size_t)node * 8 + q];
  add8(acc, us);                           // self (pre-scaled)
  // classes live in quads q<5 (cols 0..39); q>=5 quads are zeros by construction
  const bool wr = q < 5;
  float v0 = 0.f, v1 = 0.f, v2 = 0.f, v3 = 0.f, v4 = 0.f, v5 = 0.f, v6 = 0.f, v7 = 0.f;
  float m = -INFINITY;
  if (wr) {
    float d = dis[node];
    float4 ba = *(const float4*)&b2[q * 8];
    float4 bb = *(const float4*)&b2[q * 8 + 4];
    v0 = d * acc[0] + ba.x;
    v1 = d * acc[1] + ba.y;
    v2 = d * acc[2] + ba.z;
    v3 = d * acc[3] + ba.w;
    v4 = d * acc[4] + bb.x;
    v5 = d * acc[5] + bb.y;
    v6 = d * acc[6] + bb.z;
    v7 = d * acc[7] + bb.w;
    m = fmaxf(fmaxf(fmaxf(v0, v1), fmaxf(v2, v3)),
              fmaxf(fmaxf(v4, v5), fmaxf(v6, v7)));
  }
  // reduce max/sum within the 8-lane group (offsets 1,2,4 stay inside group)
#pragma unroll
  for (int off = 1; off < 8; off <<= 1) m = fmaxf(m, __shfl_xor(m, off));
  float el = 0.f;
  if (wr) {
    el = __expf(v0 - m) + __expf(v1 - m) + __expf(v2 - m) + __expf(v3 - m) +
         __expf(v4 - m) + __expf(v5 - m) + __expf(v6 - m) + __expf(v7 - m);
  }
#pragma unroll
  for (int off = 1; off < 8; off <<= 1) el += __shfl_xor(el, off);
  float ls = logf(el);
  if (wr) {
    float4 o1 = make_float4(v0 - m - ls, v1 - m - ls, v2 - m - ls, v3 - m - ls);
    float4 o2 = make_float4(v4 - m - ls, v5 - m - ls, v6 - m - ls, v7 - m - ls);
    *(float4*)&out[(size_t)node * NCLS + q * 8] = o1;
    *(float4*)&out[(size_t)node * NCLS + q * 8 + 4] = o2;
  }
}

// ---------------- launch ----------------

extern "C" void kernel_launch(void* const* d_in, const int* in_sizes, int n_in,
                              void* d_out, int out_size, void* d_ws, size_t ws_size,
                              hipStream_t stream) {
  const float* x  = (const float*)d_in[0];
  const int*   ei = (const int*)d_in[1];
  const float* W1 = (const float*)d_in[2];
  const float* b1 = (const float*)d_in[3];
  const float* W2 = (const float*)d_in[4];
  const float* b2 = (const float*)d_in[5];
  float* out = (float*)d_out;

  const int* row = ei;             // edge_index[0] = src
  const int* col = ei + N_EDGES;   // edge_index[1] = dst

  // workspace layout (~43 MB)
  int*            esrc    = (int*)d_ws;                            // ESRC_CAP ints (7.6 MB)
  unsigned int*   bktdata = (unsigned int*)(esrc + ESRC_CAP);      // NBKT*CAP      (8.0 MB)
  unsigned short* h1b     = (unsigned short*)(bktdata + (size_t)NBKT * BKT_CAP); // (N+1)*64 bf16
  unsigned short* ab      = h1b + (size_t)(N_NODES + 1) * HID;     // N*64 bf16   (12.8 MB)
  float*          dis     = (float*)(ab + (size_t)N_NODES * HID);  // N
  int*            start   = (int*)(dis + N_NODES);                 // N+1
  int*            endi    = start + N_NODES + 1;                   // N
  int*            gcur    = endi + N_NODES;                        // NBKT
  unsigned short* gb      = h1b;                                   // (N+1)*64 bf16, reuse

  k_zero<<<1, 256, 0, stream>>>(gcur, (unsigned int*)h1b);
  k_binA<<<(N_EDGES + EPB - 1) / EPB, 1024, 0, stream>>>(row, col, gcur, bktdata);
  k_build2<<<NBKT, 1024, 0, stream>>>(gcur, bktdata, dis, start, endi, esrc);

  k_gemm1<<<(N_NODES + 63) / 64, 256, 0, stream>>>(x, W1, dis, h1b);
  k_agg1<<<(N_NODES * 8 + 255) / 256, 256, 0, stream>>>(esrc, start, endi, dis, h1b, b1, ab);

  k_gemm2<<<(N_NODES + 63) / 64, 256, 0, stream>>>(ab, W2, dis, gb);
  k_agg2ls<<<(N_NODES * 8 + 255) / 256, 256, 0, stream>>>(esrc, start, endi, dis, gb, b2, out);
}